// Round 2
// baseline (1303.931 us; speedup 1.0000x reference)
//
#include <hip/hip_runtime.h>

typedef __attribute__((ext_vector_type(4))) float f32x4;

// dims: B=256, N=77, D=768, K=16, Dn=768, HID=512, L=2

// ---------------- Q = node_queries @ Wq + bq  (16x768 fp32) ----------------
// grid 48, block 256
__global__ __launch_bounds__(256) void q_kernel(const float* __restrict__ nq,
                                                const float* __restrict__ Wq,
                                                const float* __restrict__ bq,
                                                float* __restrict__ Qb) {
  int gid = blockIdx.x * 256 + threadIdx.x;  // 0..12287
  int k = gid / 768, d = gid % 768;
  const float* nr = nq + k * 768;
  float s0 = 0.f, s1 = 0.f, s2 = 0.f, s3 = 0.f;
  for (int c = 0; c < 768; c += 4) {
    s0 += nr[c + 0] * Wq[(size_t)(c + 0) * 768 + d];
    s1 += nr[c + 1] * Wq[(size_t)(c + 1) * 768 + d];
    s2 += nr[c + 2] * Wq[(size_t)(c + 2) * 768 + d];
    s3 += nr[c + 3] * Wq[(size_t)(c + 3) * 768 + d];
  }
  Qb[gid] = bq[d] + ((s0 + s1) + (s2 + s3));
}

// ---------------- fp32 GEMM: C[m][coff+n] = sum_k A[m][k]*B[k][n] + bias[n] ----------------
// A [M][K] row-major (lda=K), B [K][ldb] row-major, natural layouts. 64x64 tile,
// 256 threads, 4x4 micro-tile, BK=16. M,N multiples of 64, K multiple of 16.
__global__ __launch_bounds__(256) void gemm32(const float* __restrict__ A, int lda,
                                              const float* __restrict__ B, int ldb,
                                              const float* __restrict__ bias,
                                              float* __restrict__ C, int ldc, int coff,
                                              int K) {
  __shared__ float As[16 * 68];  // [k][m], pad 68 (row = 272B, 16B-aligned)
  __shared__ float Bs[16 * 68];  // [k][n]
  int m0 = blockIdx.x * 64, n0 = blockIdx.y * 64;
  int t = threadIdx.x;
  int tx = t & 15, ty = t >> 4;
  int ar = t >> 2, ac = (t & 3) * 4;   // A stage: row m0+ar, cols k0+ac..+3
  int br = t >> 4, bc = (t & 15) * 4;  // B stage: row k0+br, cols n0+bc..+3

  float acc[4][4] = {};

  for (int k0 = 0; k0 < K; k0 += 16) {
    f32x4 va = *(const f32x4*)&A[(size_t)(m0 + ar) * lda + k0 + ac];
    f32x4 vb = *(const f32x4*)&B[(size_t)(k0 + br) * ldb + n0 + bc];
#pragma unroll
    for (int i = 0; i < 4; ++i) As[(ac + i) * 68 + ar] = va[i];
    *(f32x4*)&Bs[br * 68 + bc] = vb;
    __syncthreads();
#pragma unroll
    for (int k = 0; k < 16; ++k) {
      f32x4 a4 = *(const f32x4*)&As[k * 68 + ty * 4];
      f32x4 b4 = *(const f32x4*)&Bs[k * 68 + tx * 4];
#pragma unroll
      for (int i = 0; i < 4; ++i)
#pragma unroll
        for (int j = 0; j < 4; ++j) acc[i][j] += a4[i] * b4[j];
    }
    __syncthreads();
  }

  f32x4 bv = {0.f, 0.f, 0.f, 0.f};
  if (bias) bv = *(const f32x4*)&bias[n0 + tx * 4];
#pragma unroll
  for (int i = 0; i < 4; ++i) {
    int m = m0 + ty * 4 + i;
    f32x4 o;
#pragma unroll
    for (int j = 0; j < 4; ++j) o[j] = acc[i][j] + bv[j];
    *(f32x4*)&C[(size_t)m * ldc + coff + n0 + tx * 4] = o;
  }
}

// ---------------- scores + softmax over K=16 -> S ----------------
// grid 256 (batch), block 256. thread: token j = t>>4 (in chunk), node k = t&15.
__global__ __launch_bounds__(256) void score_kernel(const float* __restrict__ Qb,
                                                    const float* __restrict__ Kt,
                                                    const int* __restrict__ mask,
                                                    float* __restrict__ Sout) {
  __shared__ float Qs[16 * 772];  // row pad 772 (3088B, 16B-aligned)
  int b = blockIdx.x, t = threadIdx.x;
#pragma unroll
  for (int r = 0; r < 12; ++r) {
    int idx = t + 256 * r;  // 3072 float4 chunks
    int row = idx / 192, c4 = idx % 192;
    *(f32x4*)&Qs[row * 772 + c4 * 4] = *(const f32x4*)&Qb[(size_t)row * 768 + c4 * 4];
  }
  __syncthreads();

  const float scale = 0.1020620726159658f;  // (768/8)^-0.5
  int j = t >> 4, k = t & 15;
  for (int tc = 0; tc < 5; ++tc) {
    int n = tc * 16 + j;
    int nc = n < 77 ? n : 76;
    const float* kr = Kt + (size_t)(b * 77 + nc) * 768;
    const float* qr = &Qs[k * 772];
    float s = 0.f;
#pragma unroll 4
    for (int d4 = 0; d4 < 192; ++d4) {
      f32x4 kv = *(const f32x4*)&kr[d4 * 4];
      f32x4 qv = *(const f32x4*)&qr[d4 * 4];
      s += qv[0] * kv[0] + qv[1] * kv[1] + qv[2] * kv[2] + qv[3] * kv[3];
    }
    s *= scale;
    int mk = (n < 77) ? mask[b * 77 + n] : 0;
    if (mk == 0) s = -3.402823466e38f;  // finfo(f32).min, matches reference
    // softmax over the 16 nodes = 16 consecutive lanes (k = low 4 bits of t)
    float mx = s;
#pragma unroll
    for (int off = 1; off < 16; off <<= 1) mx = fmaxf(mx, __shfl_xor(mx, off));
    float e = __expf(s - mx);
    float sm = e;
#pragma unroll
    for (int off = 1; off < 16; off <<= 1) sm += __shfl_xor(sm, off);
    if (n < 77) Sout[(size_t)b * 1232 + n * 16 + k] = e / sm;
  }
}

// ---------------- PV: V = S^T @ Vt, gate blend ----------------
// grid 256 (batch), block 256. thread owns d = t, t+256, t+512.
__global__ __launch_bounds__(256) void pv_kernel(const float* __restrict__ Sg,
                                                 const float* __restrict__ Vt,
                                                 const float* __restrict__ nq,
                                                 const float* __restrict__ gatep,
                                                 float* __restrict__ V32) {
  __shared__ float Ss[1232];
  int b = blockIdx.x, t = threadIdx.x;
#pragma unroll
  for (int r = 0; r < 5; ++r) {
    int idx = t + 256 * r;
    if (idx < 1232) Ss[idx] = Sg[(size_t)b * 1232 + idx];
  }
  __syncthreads();

  float a0[16], a1[16], a2[16];
#pragma unroll
  for (int k = 0; k < 16; ++k) { a0[k] = 0.f; a1[k] = 0.f; a2[k] = 0.f; }
  const float* vt = Vt + (size_t)b * 77 * 768;
  for (int n = 0; n < 77; ++n) {
    const float* row = vt + (size_t)n * 768;
    float g0 = row[t], g1 = row[t + 256], g2 = row[t + 512];
    const float* sr = &Ss[n * 16];
#pragma unroll
    for (int k = 0; k < 16; ++k) {
      float sk = sr[k];
      a0[k] += sk * g0; a1[k] += sk * g1; a2[k] += sk * g2;
    }
  }
  float g = gatep[0];
  float gate = 1.f / (1.f + __expf(-g));
  float og = 1.f - gate;
#pragma unroll
  for (int k = 0; k < 16; ++k) {
    float vals[3] = {a0[k], a1[k], a2[k]};
#pragma unroll
    for (int m = 0; m < 3; ++m) {
      int d = t + m * 256;
      V32[(size_t)b * 12288 + (size_t)k * 768 + d] = og * vals[m] + gate * nq[k * 768 + d];
    }
  }
}

// ---------------- edge logits (+softmax) per batch, fp32 ----------------
// HIJ [4096][1024] = (hi | hj), NO be1 included. E[i][j]=sum_h relu(hi+hj+be1)*We2 + be2
__global__ __launch_bounds__(256) void edge_kernel(const float* __restrict__ HIJ,
                                                   const float* __restrict__ be1,
                                                   const float* __restrict__ We2,
                                                   const float* __restrict__ be2v,
                                                   float* __restrict__ Aout,
                                                   float* __restrict__ Eout) {
  __shared__ float hiS[16 * 260];  // pad 260 (1040B, 16B-aligned)
  __shared__ float hjS[16 * 260];
  __shared__ float be1s[512];
  __shared__ float w2s[512];
  int b = blockIdx.x, t = threadIdx.x;
  be1s[t] = be1[t]; be1s[t + 256] = be1[t + 256];
  w2s[t] = We2[t];  w2s[t + 256] = We2[t + 256];

  int i = t >> 4, jj = t & 15;
  float e = 0.f;
  for (int half = 0; half < 2; ++half) {
    __syncthreads();
#pragma unroll
    for (int r = 0; r < 4; ++r) {
      int idx = t + 256 * r;  // 1024 float4 chunks per matrix half
      int row = idx >> 6, c4 = idx & 63;
      const float* src = &HIJ[(size_t)(b * 16 + row) * 1024 + half * 256 + c4 * 4];
      *(f32x4*)&hiS[row * 260 + c4 * 4] = *(const f32x4*)src;
      *(f32x4*)&hjS[row * 260 + c4 * 4] = *(const f32x4*)(src + 512);
    }
    __syncthreads();
    const float* hi = &hiS[i * 260];
    const float* hj = &hjS[jj * 260];
    const float* b1 = &be1s[half * 256];
    const float* w2 = &w2s[half * 256];
#pragma unroll 4
    for (int h = 0; h < 256; ++h)
      e += fmaxf(hi[h] + hj[h] + b1[h], 0.f) * w2[h];
  }
  e += be2v[0];

  if (Aout) {  // softmax over jj (16 consecutive lanes)
    float mx = e;
#pragma unroll
    for (int off = 1; off < 16; off <<= 1) mx = fmaxf(mx, __shfl_xor(mx, off));
    float ex = __expf(e - mx);
    float sm = ex;
#pragma unroll
    for (int off = 1; off < 16; off <<= 1) sm += __shfl_xor(sm, off);
    Aout[(size_t)b * 256 + t] = ex / sm;
  }
  if (Eout) Eout[(size_t)b * 256 + t] = e;
}

// ---------------- GNN combine: V += relu(A @ G) per batch ----------------
__global__ __launch_bounds__(256) void combine_kernel(const float* __restrict__ Aws,
                                                      const float* __restrict__ G,
                                                      float* __restrict__ V32,
                                                      float* __restrict__ Vout) {
  __shared__ float Gs[16 * 772];
  __shared__ float As[256];
  int b = blockIdx.x, t = threadIdx.x;
#pragma unroll
  for (int r = 0; r < 12; ++r) {
    int idx = t + 256 * r;
    int row = idx / 192, c4 = idx % 192;
    *(f32x4*)&Gs[row * 772 + c4 * 4] = *(const f32x4*)&G[(size_t)(b * 16 + row) * 768 + c4 * 4];
  }
  As[t] = Aws[(size_t)b * 256 + t];
  __syncthreads();
#pragma unroll
  for (int m = 0; m < 3; ++m) {
    int d = t + m * 256;
    float gv[16];
#pragma unroll
    for (int j = 0; j < 16; ++j) gv[j] = Gs[j * 772 + d];
#pragma unroll
    for (int i = 0; i < 16; ++i) {
      float msg = 0.f;
#pragma unroll
      for (int j = 0; j < 16; ++j) msg += As[i * 16 + j] * gv[j];
      size_t idx = (size_t)b * 12288 + (size_t)i * 768 + d;
      float v = V32[idx] + fmaxf(msg, 0.f);
      V32[idx] = v;
      if (Vout) Vout[idx] = v;
    }
  }
}

extern "C" void kernel_launch(void* const* d_in, const int* in_sizes, int n_in,
                              void* d_out, int out_size, void* d_ws, size_t ws_size,
                              hipStream_t stream) {
  const float* w    = (const float*)d_in[0];   // [256,77,768]
  const int*   mask = (const int*)d_in[1];     // [256,77]
  const float* nq   = (const float*)d_in[2];   // [1,16,768]
  const float* Wq   = (const float*)d_in[3];
  const float* bq   = (const float*)d_in[4];
  const float* Wk   = (const float*)d_in[5];
  const float* bk   = (const float*)d_in[6];
  const float* Wv   = (const float*)d_in[7];
  const float* bv   = (const float*)d_in[8];
  const float* We1  = (const float*)d_in[9];   // [1536,512]
  const float* be1  = (const float*)d_in[10];
  const float* We2  = (const float*)d_in[11];  // [512,1]
  const float* be2  = (const float*)d_in[12];
  const float* gate = (const float*)d_in[13];
  const float* Wg   = (const float*)d_in[14];  // [2,768,768]
  const float* bg   = (const float*)d_in[15];  // [2,768]

  // workspace layout (floats, ~103 MB total)
  float* ws = (float*)d_ws;
  float* Qb   = ws;                 // 12,288
  float* KtVt = Qb + 12288;         // 15,138,816  (Kt, later overwritten by Vt)
  float* HIJ  = KtVt + 15138816;    // 4,194,304
  float* Gws  = HIJ + 4194304;      // 3,145,728
  float* V32  = Gws + 3145728;      // 3,145,728
  float* Aws  = V32 + 3145728;      // 65,536

  float* out  = (float*)d_out;
  float* Sout = out;                       // [256,77,16]
  float* Vout = out + 315392;              // [256,16,768]
  float* Eout = out + 315392 + 3145728;    // [256,16,16]

  dim3 blk(256);

  // Q = nq @ Wq + bq
  q_kernel<<<48, blk, 0, stream>>>(nq, Wq, bq, Qb);

  // Kt = w @ Wk + bk ; scores+softmax -> S
  gemm32<<<dim3(308, 12), blk, 0, stream>>>(w, 768, Wk, 768, bk, KtVt, 768, 0, 768);
  score_kernel<<<256, blk, 0, stream>>>(Qb, KtVt, mask, Sout);

  // Vt = w @ Wv + bv (same buffer) ; V = S^T Vt, gate blend
  gemm32<<<dim3(308, 12), blk, 0, stream>>>(w, 768, Wv, 768, bv, KtVt, 768, 0, 768);
  pv_kernel<<<256, blk, 0, stream>>>(Sout, KtVt, nq, gate, V32);

  // pre-GNN edge logits -> A  (HIJ = [V@We1_hi | V@We1_hj], no bias)
  gemm32<<<dim3(64, 8), blk, 0, stream>>>(V32, 768, We1, 512, nullptr, HIJ, 1024, 0, 768);
  gemm32<<<dim3(64, 8), blk, 0, stream>>>(V32, 768, We1 + 768 * 512, 512, nullptr, HIJ, 1024, 512, 768);
  edge_kernel<<<256, blk, 0, stream>>>(HIJ, be1, We2, be2, Aws, (float*)nullptr);

  // GNN layer 0
  gemm32<<<dim3(64, 12), blk, 0, stream>>>(V32, 768, Wg, 768, bg, Gws, 768, 0, 768);
  combine_kernel<<<256, blk, 0, stream>>>(Aws, Gws, V32, (float*)nullptr);

  // GNN layer 1 (writes final V to d_out)
  gemm32<<<dim3(64, 12), blk, 0, stream>>>(V32, 768, Wg + 589824, 768, bg + 768, Gws, 768, 0, 768);
  combine_kernel<<<256, blk, 0, stream>>>(Aws, Gws, V32, Vout);

  // post-GNN edge logits -> E
  gemm32<<<dim3(64, 8), blk, 0, stream>>>(V32, 768, We1, 512, nullptr, HIJ, 1024, 0, 768);
  gemm32<<<dim3(64, 8), blk, 0, stream>>>(V32, 768, We1 + 768 * 512, 512, nullptr, HIJ, 1024, 512, 768);
  edge_kernel<<<256, blk, 0, stream>>>(HIJ, be1, We2, be2, (float*)nullptr, Eout);
}

// Round 3
// 564.056 us; speedup vs baseline: 2.3117x; 2.3117x over previous
//
#include <hip/hip_runtime.h>

typedef unsigned short u16;
typedef __attribute__((ext_vector_type(8))) short short8;
typedef __attribute__((ext_vector_type(4))) float f32x4;

#define DEV static __device__ __forceinline__

DEV float bf2f(u16 u) { return __uint_as_float(((unsigned)u) << 16); }
DEV u16 f2bf(float f) {
  unsigned u = __float_as_uint(f);
  return (u16)((u + 0x7fffu + ((u >> 16) & 1u)) >> 16);
}

// dims: B=256, N=77, D=768, K=16, Dn=768, HID=512, L=2

// ---------------- transpose+cast: dst_bf16[c][r] = src_f32[r][c] ----------------
// grid (C/32, R/32), block 256
__global__ __launch_bounds__(256) void tcast_k(const float* __restrict__ src,
                                               u16* __restrict__ dst,
                                               int ldS, int ldD) {
  __shared__ float tile[32][33];
  int r0 = blockIdx.y * 32, c0 = blockIdx.x * 32;
  int tr = threadIdx.x >> 5, tc = threadIdx.x & 31;
#pragma unroll
  for (int rr = 0; rr < 4; ++rr)
    tile[tr + rr * 8][tc] = src[(size_t)(r0 + tr + rr * 8) * ldS + c0 + tc];
  __syncthreads();
#pragma unroll
  for (int rr = 0; rr < 4; ++rr)
    dst[(size_t)(c0 + tr + rr * 8) * ldD + r0 + tc] = f2bf(tile[tc][tr + rr * 8]);
}

// ---------------- Q = node_queries @ Wq + bq  (16x768 fp32) ----------------
__global__ __launch_bounds__(256) void q_kernel(const float* __restrict__ nq,
                                                const float* __restrict__ Wq,
                                                const float* __restrict__ bq,
                                                float* __restrict__ Qb) {
  int gid = blockIdx.x * 256 + threadIdx.x;  // 0..12287
  int k = gid / 768, d = gid % 768;
  const float* nr = nq + k * 768;
  float s0 = 0.f, s1 = 0.f, s2 = 0.f, s3 = 0.f;
  for (int c = 0; c < 768; c += 4) {
    s0 += nr[c + 0] * Wq[(size_t)(c + 0) * 768 + d];
    s1 += nr[c + 1] * Wq[(size_t)(c + 1) * 768 + d];
    s2 += nr[c + 2] * Wq[(size_t)(c + 2) * 768 + d];
    s3 += nr[c + 3] * Wq[(size_t)(c + 3) * 768 + d];
  }
  Qb[gid] = bq[d] + ((s0 + s1) + (s2 + s3));
}

// ---------------- MFMA GEMM: C[m][n] = sum_k A32[m][k]*BT[n][k] + bias(n) ----------------
// A fp32 [M][K] row-major (converted bf16 during staging), BT bf16 [N][K] row-major.
// C bf16 (c_bf16=1) or fp32. bias(n) = n<Nh ? bias0[n] : bias1[n-Nh] (nullptr -> 0).
// grid (M/128, N/128), block 256 (4 waves, 2x2 of 64x64, each wave 4x4 mfma 16x16x32)
__global__ __launch_bounds__(256) void gemm_bt(const float* __restrict__ A,
                                               const u16* __restrict__ BT,
                                               const float* __restrict__ bias0,
                                               const float* __restrict__ bias1, int Nh,
                                               void* __restrict__ C, int c_bf16,
                                               int N, int K) {
  const int LDK = 40;  // 32 + 8 pad
  __shared__ u16 As[128 * LDK];
  __shared__ u16 Bs[128 * LDK];
  int m0 = blockIdx.x * 128, n0 = blockIdx.y * 128;
  int t = threadIdx.x;
  int wave = t >> 6, lane = t & 63, l16 = lane & 15, quad = lane >> 4;
  int wrow = (wave >> 1) * 64, wcol = (wave & 1) * 64;
  int srow = t >> 2, scol = (t & 3) * 8;

  f32x4 zero4 = {0.f, 0.f, 0.f, 0.f};
  f32x4 acc[4][4];
#pragma unroll
  for (int i = 0; i < 4; ++i)
#pragma unroll
    for (int j = 0; j < 4; ++j) acc[i][j] = zero4;

  for (int k0 = 0; k0 < K; k0 += 32) {
    // A: load fp32, convert to bf16, stage
    const float* ap = A + (size_t)(m0 + srow) * K + k0 + scol;
#pragma unroll
    for (int h = 0; h < 2; ++h) {
      f32x4 lo = *(const f32x4*)(ap + (size_t)h * 64 * K);
      f32x4 hi = *(const f32x4*)(ap + (size_t)h * 64 * K + 4);
      short8 cv;
#pragma unroll
      for (int e = 0; e < 4; ++e) { cv[e] = (short)f2bf(lo[e]); cv[e + 4] = (short)f2bf(hi[e]); }
      *(short8*)&As[(srow + h * 64) * LDK + scol] = cv;
    }
    // B: bf16 direct
    const u16* bp = BT + (size_t)(n0 + srow) * K + k0 + scol;
    *(short8*)&Bs[srow * LDK + scol] = *(const short8*)bp;
    *(short8*)&Bs[(srow + 64) * LDK + scol] = *(const short8*)(bp + (size_t)64 * K);
    __syncthreads();
    short8 fa[4], fb[4];
#pragma unroll
    for (int i = 0; i < 4; ++i)
      fa[i] = *(const short8*)&As[(wrow + i * 16 + l16) * LDK + quad * 8];
#pragma unroll
    for (int j = 0; j < 4; ++j)
      fb[j] = *(const short8*)&Bs[(wcol + j * 16 + l16) * LDK + quad * 8];
#pragma unroll
    for (int i = 0; i < 4; ++i)
#pragma unroll
      for (int j = 0; j < 4; ++j)
        acc[i][j] = __builtin_amdgcn_mfma_f32_16x16x32_bf16(fa[i], fb[j], acc[i][j], 0, 0, 0);
    __syncthreads();
  }

#pragma unroll
  for (int j = 0; j < 4; ++j) {
    int n = n0 + wcol + j * 16 + l16;
    float bv = 0.f;
    if (bias0) bv = (n < Nh) ? bias0[n] : bias1[n - Nh];
#pragma unroll
    for (int i = 0; i < 4; ++i)
#pragma unroll
      for (int r = 0; r < 4; ++r) {
        int m = m0 + wrow + i * 16 + quad * 4 + r;
        float v = acc[i][j][r] + bv;
        if (c_bf16) ((u16*)C)[(size_t)m * N + n] = f2bf(v);
        else        ((float*)C)[(size_t)m * N + n] = v;
      }
  }
}

// ---------------- scores + softmax over K=16 -> S ----------------
// KV bf16 [B*77][1536] (Kt | Vt). grid 256 (batch), block 256.
__global__ __launch_bounds__(256) void score_kernel(const float* __restrict__ Qb,
                                                    const u16* __restrict__ KV,
                                                    const int* __restrict__ mask,
                                                    float* __restrict__ Sout) {
  __shared__ float Qs[16 * 772];
  int b = blockIdx.x, t = threadIdx.x;
#pragma unroll
  for (int r = 0; r < 12; ++r) {
    int idx = t + 256 * r;  // 3072 float4 chunks
    int row = idx / 192, c4 = idx % 192;
    *(f32x4*)&Qs[row * 772 + c4 * 4] = *(const f32x4*)&Qb[(size_t)row * 768 + c4 * 4];
  }
  __syncthreads();

  const float scale = 0.1020620726159658f;  // (768/8)^-0.5
  int j = t >> 4, k = t & 15;
  for (int tc = 0; tc < 5; ++tc) {
    int n = tc * 16 + j;
    int nc = n < 77 ? n : 76;
    const u16* kr = KV + (size_t)(b * 77 + nc) * 1536;  // Kt half
    const float* qr = &Qs[k * 772];
    float s = 0.f;
#pragma unroll 2
    for (int d8 = 0; d8 < 96; ++d8) {
      short8 kv8 = *(const short8*)&kr[d8 * 8];
      f32x4 q0 = *(const f32x4*)&qr[d8 * 8];
      f32x4 q1 = *(const f32x4*)&qr[d8 * 8 + 4];
#pragma unroll
      for (int e = 0; e < 4; ++e) s += q0[e] * bf2f((u16)kv8[e]);
#pragma unroll
      for (int e = 0; e < 4; ++e) s += q1[e] * bf2f((u16)kv8[e + 4]);
    }
    s *= scale;
    int mk = (n < 77) ? mask[b * 77 + n] : 0;
    if (mk == 0) s = -3.402823466e38f;  // finfo(f32).min, matches reference
    float mx = s;
#pragma unroll
    for (int off = 1; off < 16; off <<= 1) mx = fmaxf(mx, __shfl_xor(mx, off));
    float e = __expf(s - mx);
    float sm = e;
#pragma unroll
    for (int off = 1; off < 16; off <<= 1) sm += __shfl_xor(sm, off);
    if (n < 77) Sout[(size_t)b * 1232 + n * 16 + k] = e / sm;
  }
}

// ---------------- PV: V = S^T @ Vt, gate blend ----------------
__global__ __launch_bounds__(256) void pv_kernel(const float* __restrict__ Sg,
                                                 const u16* __restrict__ KV,
                                                 const float* __restrict__ nq,
                                                 const float* __restrict__ gatep,
                                                 float* __restrict__ V32) {
  __shared__ float Ss[1232];
  int b = blockIdx.x, t = threadIdx.x;
#pragma unroll
  for (int r = 0; r < 5; ++r) {
    int idx = t + 256 * r;
    if (idx < 1232) Ss[idx] = Sg[(size_t)b * 1232 + idx];
  }
  __syncthreads();

  float a0[16], a1[16], a2[16];
#pragma unroll
  for (int k = 0; k < 16; ++k) { a0[k] = 0.f; a1[k] = 0.f; a2[k] = 0.f; }
  const u16* vt = KV + (size_t)b * 77 * 1536 + 768;  // Vt half
  for (int n = 0; n < 77; ++n) {
    const u16* row = vt + (size_t)n * 1536;
    float g0 = bf2f(row[t]), g1 = bf2f(row[t + 256]), g2 = bf2f(row[t + 512]);
    const float* sr = &Ss[n * 16];
#pragma unroll
    for (int k = 0; k < 16; ++k) {
      float sk = sr[k];
      a0[k] += sk * g0; a1[k] += sk * g1; a2[k] += sk * g2;
    }
  }
  float g = gatep[0];
  float gate = 1.f / (1.f + __expf(-g));
  float og = 1.f - gate;
#pragma unroll
  for (int k = 0; k < 16; ++k) {
    float vals[3] = {a0[k], a1[k], a2[k]};
#pragma unroll
    for (int m = 0; m < 3; ++m) {
      int d = t + m * 256;
      V32[(size_t)b * 12288 + (size_t)k * 768 + d] = og * vals[m] + gate * nq[k * 768 + d];
    }
  }
}

// ---------------- edge logits (+softmax) per batch, fp32 ----------------
// HIJ fp32 [4096][1024] = (hi | hj), no be1. E[i][j]=sum_h relu(hi+hj+be1)*We2 + be2
__global__ __launch_bounds__(256) void edge_kernel(const float* __restrict__ HIJ,
                                                   const float* __restrict__ be1,
                                                   const float* __restrict__ We2,
                                                   const float* __restrict__ be2v,
                                                   float* __restrict__ Aout,
                                                   float* __restrict__ Eout) {
  __shared__ float hiS[16 * 260];
  __shared__ float hjS[16 * 260];
  __shared__ float be1s[512];
  __shared__ float w2s[512];
  int b = blockIdx.x, t = threadIdx.x;
  be1s[t] = be1[t]; be1s[t + 256] = be1[t + 256];
  w2s[t] = We2[t];  w2s[t + 256] = We2[t + 256];

  int i = t >> 4, jj = t & 15;
  float e = 0.f;
  for (int half = 0; half < 2; ++half) {
    __syncthreads();
#pragma unroll
    for (int r = 0; r < 4; ++r) {
      int idx = t + 256 * r;  // 1024 float4 chunks per half
      int row = idx >> 6, c4 = idx & 63;
      const float* src = &HIJ[(size_t)(b * 16 + row) * 1024 + half * 256 + c4 * 4];
      *(f32x4*)&hiS[row * 260 + c4 * 4] = *(const f32x4*)src;
      *(f32x4*)&hjS[row * 260 + c4 * 4] = *(const f32x4*)(src + 512);
    }
    __syncthreads();
    const float* hi = &hiS[i * 260];
    const float* hj = &hjS[jj * 260];
    const float* b1 = &be1s[half * 256];
    const float* w2 = &w2s[half * 256];
#pragma unroll 4
    for (int h = 0; h < 256; ++h)
      e += fmaxf(hi[h] + hj[h] + b1[h], 0.f) * w2[h];
  }
  e += be2v[0];

  if (Aout) {
    float mx = e;
#pragma unroll
    for (int off = 1; off < 16; off <<= 1) mx = fmaxf(mx, __shfl_xor(mx, off));
    float ex = __expf(e - mx);
    float sm = ex;
#pragma unroll
    for (int off = 1; off < 16; off <<= 1) sm += __shfl_xor(sm, off);
    Aout[(size_t)b * 256 + t] = ex / sm;
  }
  if (Eout) Eout[(size_t)b * 256 + t] = e;
}

// ---------------- GNN combine: V += relu(A @ G) per batch ----------------
__global__ __launch_bounds__(256) void combine_kernel(const float* __restrict__ Aws,
                                                      const float* __restrict__ G,
                                                      float* __restrict__ V32,
                                                      float* __restrict__ Vout) {
  __shared__ float Gs[16 * 772];
  __shared__ float As[256];
  int b = blockIdx.x, t = threadIdx.x;
#pragma unroll
  for (int r = 0; r < 12; ++r) {
    int idx = t + 256 * r;
    int row = idx / 192, c4 = idx % 192;
    *(f32x4*)&Gs[row * 772 + c4 * 4] = *(const f32x4*)&G[(size_t)(b * 16 + row) * 768 + c4 * 4];
  }
  As[t] = Aws[(size_t)b * 256 + t];
  __syncthreads();
#pragma unroll
  for (int m = 0; m < 3; ++m) {
    int d = t + m * 256;
    float gv[16];
#pragma unroll
    for (int j = 0; j < 16; ++j) gv[j] = Gs[j * 772 + d];
#pragma unroll
    for (int i = 0; i < 16; ++i) {
      float msg = 0.f;
#pragma unroll
      for (int j = 0; j < 16; ++j) msg += As[i * 16 + j] * gv[j];
      size_t idx = (size_t)b * 12288 + (size_t)i * 768 + d;
      float v = V32[idx] + fmaxf(msg, 0.f);
      V32[idx] = v;
      if (Vout) Vout[idx] = v;
    }
  }
}

extern "C" void kernel_launch(void* const* d_in, const int* in_sizes, int n_in,
                              void* d_out, int out_size, void* d_ws, size_t ws_size,
                              hipStream_t stream) {
  const float* w    = (const float*)d_in[0];   // [256,77,768]
  const int*   mask = (const int*)d_in[1];     // [256,77]
  const float* nq   = (const float*)d_in[2];   // [1,16,768]
  const float* Wq   = (const float*)d_in[3];
  const float* bq   = (const float*)d_in[4];
  const float* Wk   = (const float*)d_in[5];
  const float* bk   = (const float*)d_in[6];
  const float* Wv   = (const float*)d_in[7];
  const float* bv   = (const float*)d_in[8];
  const float* We1  = (const float*)d_in[9];   // [1536,512]
  const float* be1  = (const float*)d_in[10];
  const float* We2  = (const float*)d_in[11];  // [512,1]
  const float* be2  = (const float*)d_in[12];
  const float* gate = (const float*)d_in[13];
  const float* Wg   = (const float*)d_in[14];  // [2,768,768]
  const float* bg   = (const float*)d_in[15];  // [2,768]

  // workspace (float slots; ~80 MB total)
  float* ws  = (float*)d_ws;
  float* Qb  = ws;                  // 12,288
  float* V32 = Qb + 12288;          // 3,145,728
  float* Aws = V32 + 3145728;       // 65,536
  u16* WkvT  = (u16*)(Aws + 65536); // [1536][768] bf16
  u16* We1T  = WkvT + 1179648;      // [1024][768] bf16
  u16* WgT   = We1T + 786432;       // [2][768][768] bf16
  // union region: KV bf16 [19712][1536] (alive: KV gemm .. pv)
  //            OR HIJ fp32 [4096][1024] + G fp32 [4096][768] (alive after pv)
  u16* KV    = WgT + 1179648;       // 30,277,632 u16 = 15,138,816 f
  float* HIJ = (float*)KV;          // 4,194,304 f
  float* Gws = HIJ + 4194304;       // 3,145,728 f

  float* out  = (float*)d_out;
  float* Sout = out;                       // [256,77,16]
  float* Vout = out + 315392;              // [256,16,768]
  float* Eout = out + 315392 + 3145728;    // [256,16,16]

  dim3 blk(256);

  // weights -> bf16 transposed [n][k]
  tcast_k<<<dim3(24, 24), blk, 0, stream>>>(Wk, WkvT, 768, 768);
  tcast_k<<<dim3(24, 24), blk, 0, stream>>>(Wv, WkvT + 589824, 768, 768);
  tcast_k<<<dim3(16, 24), blk, 0, stream>>>(We1, We1T, 512, 768);
  tcast_k<<<dim3(16, 24), blk, 0, stream>>>(We1 + 768 * 512, We1T + 512 * 768, 512, 768);
  tcast_k<<<dim3(24, 24), blk, 0, stream>>>(Wg, WgT, 768, 768);
  tcast_k<<<dim3(24, 24), blk, 0, stream>>>(Wg + 589824, WgT + 589824, 768, 768);

  // Q = nq @ Wq + bq (fp32)
  q_kernel<<<48, blk, 0, stream>>>(nq, Wq, bq, Qb);

  // KV = w @ (Wk|Wv) + (bk|bv), bf16 out [19712][1536]
  gemm_bt<<<dim3(154, 12), blk, 0, stream>>>(w, WkvT, bk, bv, 768, KV, 1, 1536, 768);

  // attention
  score_kernel<<<256, blk, 0, stream>>>(Qb, KV, mask, Sout);
  pv_kernel<<<256, blk, 0, stream>>>(Sout, KV, nq, gate, V32);

  // pre-GNN edge logits -> A   (HIJ = [V@We1_hi | V@We1_hj], fp32, no bias)
  gemm_bt<<<dim3(32, 8), blk, 0, stream>>>(V32, We1T, nullptr, nullptr, 0, HIJ, 0, 1024, 768);
  edge_kernel<<<256, blk, 0, stream>>>(HIJ, be1, We2, be2, Aws, (float*)nullptr);

  // GNN layer 0
  gemm_bt<<<dim3(32, 6), blk, 0, stream>>>(V32, WgT, bg, bg, 768, Gws, 0, 768, 768);
  combine_kernel<<<256, blk, 0, stream>>>(Aws, Gws, V32, (float*)nullptr);

  // GNN layer 1 (writes final V to d_out)
  gemm_bt<<<dim3(32, 6), blk, 0, stream>>>(V32, WgT + 589824, bg + 768, bg + 768, 768, Gws, 0, 768, 768);
  combine_kernel<<<256, blk, 0, stream>>>(Aws, Gws, V32, Vout);

  // post-GNN edge logits -> E
  gemm_bt<<<dim3(32, 8), blk, 0, stream>>>(V32, We1T, nullptr, nullptr, 0, HIJ, 0, 1024, 768);
  edge_kernel<<<256, blk, 0, stream>>>(HIJ, be1, We2, be2, (float*)nullptr, Eout);
}

// Round 4
// 552.954 us; speedup vs baseline: 2.3581x; 1.0201x over previous
//
#include <hip/hip_runtime.h>

typedef unsigned short u16;
typedef __attribute__((ext_vector_type(8))) short short8;
typedef __attribute__((ext_vector_type(4))) float f32x4;

#define DEV static __device__ __forceinline__

DEV float bf2f(u16 u) { return __uint_as_float(((unsigned)u) << 16); }
DEV u16 f2bf(float f) {
  unsigned u = __float_as_uint(f);
  return (u16)((u + 0x7fffu + ((u >> 16) & 1u)) >> 16);
}

// async global->LDS, 16B per lane; lds must be wave-uniform, lane i lands at lds + i*16
DEV void cp16(void* lds, const void* g) {
  __builtin_amdgcn_global_load_lds(
      (const __attribute__((address_space(1))) unsigned int*)g,
      (__attribute__((address_space(3))) unsigned int*)lds, 16, 0, 0);
}

// dims: B=256, N=77, D=768, K=16, Dn=768, HID=512, L=2

// ---------------- cast fp32 -> bf16, 8 elems/thread ----------------
__global__ __launch_bounds__(256) void wcast_k(const float* __restrict__ src,
                                               u16* __restrict__ dst, int n8) {
  int i = blockIdx.x * 256 + threadIdx.x;
  if (i >= n8) return;
  f32x4 a = *(const f32x4*)&src[(size_t)i * 8];
  f32x4 b = *(const f32x4*)&src[(size_t)i * 8 + 4];
  short8 o;
#pragma unroll
  for (int e = 0; e < 4; ++e) { o[e] = (short)f2bf(a[e]); o[e + 4] = (short)f2bf(b[e]); }
  *(short8*)&dst[(size_t)i * 8] = o;
}

// ---------------- all weight transposes+casts in one launch ----------------
// z selects matrix; src [768][C] fp32 -> dst [C][768] bf16. grid (24,24,6)
__global__ __launch_bounds__(256) void tcast_all(const float* __restrict__ Wk,
                                                 const float* __restrict__ Wv,
                                                 const float* __restrict__ We1,
                                                 const float* __restrict__ Wg,
                                                 u16* __restrict__ WkvT,
                                                 u16* __restrict__ We1T,
                                                 u16* __restrict__ WgT) {
  __shared__ float tile[32][33];
  const float* src; u16* dst; int C;
  switch (blockIdx.z) {
    case 0: src = Wk;           dst = WkvT;          C = 768; break;
    case 1: src = Wv;           dst = WkvT + 589824; C = 768; break;
    case 2: src = We1;          dst = We1T;          C = 512; break;
    case 3: src = We1 + 393216; dst = We1T + 393216; C = 512; break;
    case 4: src = Wg;           dst = WgT;           C = 768; break;
    default: src = Wg + 589824; dst = WgT + 589824;  C = 768; break;
  }
  int r0 = blockIdx.y * 32, c0 = blockIdx.x * 32;
  if (c0 >= C) return;
  int tr = threadIdx.x >> 5, tc = threadIdx.x & 31;
#pragma unroll
  for (int rr = 0; rr < 4; ++rr)
    tile[tr + rr * 8][tc] = src[(size_t)(r0 + tr + rr * 8) * C + c0 + tc];
  __syncthreads();
#pragma unroll
  for (int rr = 0; rr < 4; ++rr)
    dst[(size_t)(c0 + tr + rr * 8) * 768 + r0 + tc] = f2bf(tile[tc][tr + rr * 8]);
}

// ---------------- Q = node_queries @ Wq + bq  (16x768 fp32) ----------------
__global__ __launch_bounds__(256) void q_kernel(const float* __restrict__ nq,
                                                const float* __restrict__ Wq,
                                                const float* __restrict__ bq,
                                                float* __restrict__ Qb) {
  int gid = blockIdx.x * 256 + threadIdx.x;  // 0..12287
  int k = gid / 768, d = gid % 768;
  const float* nr = nq + k * 768;
  float s0 = 0.f, s1 = 0.f, s2 = 0.f, s3 = 0.f;
  for (int c = 0; c < 768; c += 4) {
    s0 += nr[c + 0] * Wq[(size_t)(c + 0) * 768 + d];
    s1 += nr[c + 1] * Wq[(size_t)(c + 1) * 768 + d];
    s2 += nr[c + 2] * Wq[(size_t)(c + 2) * 768 + d];
    s3 += nr[c + 3] * Wq[(size_t)(c + 3) * 768 + d];
  }
  Qb[gid] = bq[d] + ((s0 + s1) + (s2 + s3));
}

// ---------------- pure-bf16 MFMA GEMM with async LDS staging ----------------
// A bf16 [M][K], BT bf16 [N][K], C bf16 = A@BT^T + bias. 128x128 tile, BK=32,
// unpadded LDS (required by global_load_lds lane layout). grid (M/128, N/128).
__global__ __launch_bounds__(256) void gemm16(const u16* __restrict__ A,
                                              const u16* __restrict__ BT,
                                              const float* __restrict__ bias,
                                              u16* __restrict__ C, int N, int K) {
  __shared__ u16 As[128 * 32];
  __shared__ u16 Bs[128 * 32];
  int m0 = blockIdx.x * 128, n0 = blockIdx.y * 128;
  int t = threadIdx.x;
  int wave = t >> 6, lane = t & 63, l16 = lane & 15, quad = lane >> 4;
  int wrow = (wave >> 1) * 64, wcol = (wave & 1) * 64;
  // staging: wave handles rows [wave*32, wave*32+32), two 16-row instructions
  int srow = wave * 32 + (lane >> 2);  // +q*16
  int scol = (lane & 3) * 8;           // u16 units = 16B

  f32x4 zero4 = {0.f, 0.f, 0.f, 0.f};
  f32x4 acc[4][4];
#pragma unroll
  for (int i = 0; i < 4; ++i)
#pragma unroll
    for (int j = 0; j < 4; ++j) acc[i][j] = zero4;

  for (int k0 = 0; k0 < K; k0 += 32) {
    const u16* ga = A + (size_t)(m0 + srow) * K + k0 + scol;
    const u16* gb = BT + (size_t)(n0 + srow) * K + k0 + scol;
    cp16(&As[(wave * 32) * 32], ga);
    cp16(&As[(wave * 32 + 16) * 32], ga + (size_t)16 * K);
    cp16(&Bs[(wave * 32) * 32], gb);
    cp16(&Bs[(wave * 32 + 16) * 32], gb + (size_t)16 * K);
    __syncthreads();
    short8 fa[4], fb[4];
#pragma unroll
    for (int i = 0; i < 4; ++i)
      fa[i] = *(const short8*)&As[(wrow + i * 16 + l16) * 32 + quad * 8];
#pragma unroll
    for (int j = 0; j < 4; ++j)
      fb[j] = *(const short8*)&Bs[(wcol + j * 16 + l16) * 32 + quad * 8];
#pragma unroll
    for (int i = 0; i < 4; ++i)
#pragma unroll
      for (int j = 0; j < 4; ++j)
        acc[i][j] = __builtin_amdgcn_mfma_f32_16x16x32_bf16(fa[i], fb[j], acc[i][j], 0, 0, 0);
    __syncthreads();
  }

#pragma unroll
  for (int j = 0; j < 4; ++j) {
    int n = n0 + wcol + j * 16 + l16;
    float bv = bias ? bias[n] : 0.f;
#pragma unroll
    for (int i = 0; i < 4; ++i)
#pragma unroll
      for (int r = 0; r < 4; ++r) {
        int m = m0 + wrow + i * 16 + quad * 4 + r;
        C[(size_t)m * N + n] = f2bf(acc[i][j][r] + bv);
      }
  }
}

// ---------------- fp32-A MFMA GEMM (for V32-input small GEMMs) ----------------
// A fp32 [M][K] (converted bf16 in staging), BT bf16 [N][K], C fp32.
// bias(n) = n<Nh ? bias0[n] : bias1[n-Nh] (nullptr -> 0). grid (M/128, N/128).
__global__ __launch_bounds__(256) void gemm_bt(const float* __restrict__ A,
                                               const u16* __restrict__ BT,
                                               const float* __restrict__ bias0,
                                               const float* __restrict__ bias1, int Nh,
                                               float* __restrict__ C, int N, int K) {
  const int LDK = 40;  // 32 + 8 pad
  __shared__ u16 As[128 * LDK];
  __shared__ u16 Bs[128 * LDK];
  int m0 = blockIdx.x * 128, n0 = blockIdx.y * 128;
  int t = threadIdx.x;
  int wave = t >> 6, lane = t & 63, l16 = lane & 15, quad = lane >> 4;
  int wrow = (wave >> 1) * 64, wcol = (wave & 1) * 64;
  int srow = t >> 2, scol = (t & 3) * 8;

  f32x4 zero4 = {0.f, 0.f, 0.f, 0.f};
  f32x4 acc[4][4];
#pragma unroll
  for (int i = 0; i < 4; ++i)
#pragma unroll
    for (int j = 0; j < 4; ++j) acc[i][j] = zero4;

  for (int k0 = 0; k0 < K; k0 += 32) {
    const float* ap = A + (size_t)(m0 + srow) * K + k0 + scol;
#pragma unroll
    for (int h = 0; h < 2; ++h) {
      f32x4 lo = *(const f32x4*)(ap + (size_t)h * 64 * K);
      f32x4 hi = *(const f32x4*)(ap + (size_t)h * 64 * K + 4);
      short8 cv;
#pragma unroll
      for (int e = 0; e < 4; ++e) { cv[e] = (short)f2bf(lo[e]); cv[e + 4] = (short)f2bf(hi[e]); }
      *(short8*)&As[(srow + h * 64) * LDK + scol] = cv;
    }
    const u16* bp = BT + (size_t)(n0 + srow) * K + k0 + scol;
    *(short8*)&Bs[srow * LDK + scol] = *(const short8*)bp;
    *(short8*)&Bs[(srow + 64) * LDK + scol] = *(const short8*)(bp + (size_t)64 * K);
    __syncthreads();
    short8 fa[4], fb[4];
#pragma unroll
    for (int i = 0; i < 4; ++i)
      fa[i] = *(const short8*)&As[(wrow + i * 16 + l16) * LDK + quad * 8];
#pragma unroll
    for (int j = 0; j < 4; ++j)
      fb[j] = *(const short8*)&Bs[(wcol + j * 16 + l16) * LDK + quad * 8];
#pragma unroll
    for (int i = 0; i < 4; ++i)
#pragma unroll
      for (int j = 0; j < 4; ++j)
        acc[i][j] = __builtin_amdgcn_mfma_f32_16x16x32_bf16(fa[i], fb[j], acc[i][j], 0, 0, 0);
    __syncthreads();
  }

#pragma unroll
  for (int j = 0; j < 4; ++j) {
    int n = n0 + wcol + j * 16 + l16;
    float bv = 0.f;
    if (bias0) bv = (n < Nh) ? bias0[n] : bias1[n - Nh];
#pragma unroll
    for (int i = 0; i < 4; ++i)
#pragma unroll
      for (int r = 0; r < 4; ++r) {
        int m = m0 + wrow + i * 16 + quad * 4 + r;
        C[(size_t)m * N + n] = acc[i][j][r] + bv;
      }
  }
}

// ---------------- scores + softmax over K=16 -> S ----------------
// Kt bf16 [B*77][768]. grid 256 (batch), block 256.
__global__ __launch_bounds__(256) void score_kernel(const float* __restrict__ Qb,
                                                    const u16* __restrict__ Kt,
                                                    const int* __restrict__ mask,
                                                    float* __restrict__ Sout) {
  __shared__ float Qs[16 * 772];
  int b = blockIdx.x, t = threadIdx.x;
#pragma unroll
  for (int r = 0; r < 12; ++r) {
    int idx = t + 256 * r;  // 3072 float4 chunks
    int row = idx / 192, c4 = idx % 192;
    *(f32x4*)&Qs[row * 772 + c4 * 4] = *(const f32x4*)&Qb[(size_t)row * 768 + c4 * 4];
  }
  __syncthreads();

  const float scale = 0.1020620726159658f;  // (768/8)^-0.5
  int j = t >> 4, k = t & 15;
  for (int tc = 0; tc < 5; ++tc) {
    int n = tc * 16 + j;
    int nc = n < 77 ? n : 76;
    const u16* kr = Kt + (size_t)(b * 77 + nc) * 768;
    const float* qr = &Qs[k * 772];
    float s = 0.f;
#pragma unroll 2
    for (int d8 = 0; d8 < 96; ++d8) {
      short8 kv8 = *(const short8*)&kr[d8 * 8];
      f32x4 q0 = *(const f32x4*)&qr[d8 * 8];
      f32x4 q1 = *(const f32x4*)&qr[d8 * 8 + 4];
#pragma unroll
      for (int e = 0; e < 4; ++e) s += q0[e] * bf2f((u16)kv8[e]);
#pragma unroll
      for (int e = 0; e < 4; ++e) s += q1[e] * bf2f((u16)kv8[e + 4]);
    }
    s *= scale;
    int mk = (n < 77) ? mask[b * 77 + n] : 0;
    if (mk == 0) s = -3.402823466e38f;  // finfo(f32).min, matches reference
    float mx = s;
#pragma unroll
    for (int off = 1; off < 16; off <<= 1) mx = fmaxf(mx, __shfl_xor(mx, off));
    float e = __expf(s - mx);
    float sm = e;
#pragma unroll
    for (int off = 1; off < 16; off <<= 1) sm += __shfl_xor(sm, off);
    if (n < 77) Sout[(size_t)b * 1232 + n * 16 + k] = e / sm;
  }
}

// ---------------- PV: V = S^T @ Vt, gate blend ----------------
// Vt bf16 [B*77][768]
__global__ __launch_bounds__(256) void pv_kernel(const float* __restrict__ Sg,
                                                 const u16* __restrict__ Vt,
                                                 const float* __restrict__ nq,
                                                 const float* __restrict__ gatep,
                                                 float* __restrict__ V32) {
  __shared__ float Ss[1232];
  int b = blockIdx.x, t = threadIdx.x;
#pragma unroll
  for (int r = 0; r < 5; ++r) {
    int idx = t + 256 * r;
    if (idx < 1232) Ss[idx] = Sg[(size_t)b * 1232 + idx];
  }
  __syncthreads();

  float a0[16], a1[16], a2[16];
#pragma unroll
  for (int k = 0; k < 16; ++k) { a0[k] = 0.f; a1[k] = 0.f; a2[k] = 0.f; }
  const u16* vt = Vt + (size_t)b * 77 * 768;
  for (int n = 0; n < 77; ++n) {
    const u16* row = vt + (size_t)n * 768;
    float g0 = bf2f(row[t]), g1 = bf2f(row[t + 256]), g2 = bf2f(row[t + 512]);
    const float* sr = &Ss[n * 16];
#pragma unroll
    for (int k = 0; k < 16; ++k) {
      float sk = sr[k];
      a0[k] += sk * g0; a1[k] += sk * g1; a2[k] += sk * g2;
    }
  }
  float g = gatep[0];
  float gate = 1.f / (1.f + __expf(-g));
  float og = 1.f - gate;
#pragma unroll
  for (int k = 0; k < 16; ++k) {
    float vals[3] = {a0[k], a1[k], a2[k]};
#pragma unroll
    for (int m = 0; m < 3; ++m) {
      int d = t + m * 256;
      V32[(size_t)b * 12288 + (size_t)k * 768 + d] = og * vals[m] + gate * nq[k * 768 + d];
    }
  }
}

// ---------------- edge logits (+softmax) per batch, fp32 ----------------
__global__ __launch_bounds__(256) void edge_kernel(const float* __restrict__ HIJ,
                                                   const float* __restrict__ be1,
                                                   const float* __restrict__ We2,
                                                   const float* __restrict__ be2v,
                                                   float* __restrict__ Aout,
                                                   float* __restrict__ Eout) {
  __shared__ float hiS[16 * 260];
  __shared__ float hjS[16 * 260];
  __shared__ float be1s[512];
  __shared__ float w2s[512];
  int b = blockIdx.x, t = threadIdx.x;
  be1s[t] = be1[t]; be1s[t + 256] = be1[t + 256];
  w2s[t] = We2[t];  w2s[t + 256] = We2[t + 256];

  int i = t >> 4, jj = t & 15;
  float e = 0.f;
  for (int half = 0; half < 2; ++half) {
    __syncthreads();
#pragma unroll
    for (int r = 0; r < 4; ++r) {
      int idx = t + 256 * r;
      int row = idx >> 6, c4 = idx & 63;
      const float* src = &HIJ[(size_t)(b * 16 + row) * 1024 + half * 256 + c4 * 4];
      *(f32x4*)&hiS[row * 260 + c4 * 4] = *(const f32x4*)src;
      *(f32x4*)&hjS[row * 260 + c4 * 4] = *(const f32x4*)(src + 512);
    }
    __syncthreads();
    const float* hi = &hiS[i * 260];
    const float* hj = &hjS[jj * 260];
    const float* b1 = &be1s[half * 256];
    const float* w2 = &w2s[half * 256];
#pragma unroll 4
    for (int h = 0; h < 256; ++h)
      e += fmaxf(hi[h] + hj[h] + b1[h], 0.f) * w2[h];
  }
  e += be2v[0];

  if (Aout) {
    float mx = e;
#pragma unroll
    for (int off = 1; off < 16; off <<= 1) mx = fmaxf(mx, __shfl_xor(mx, off));
    float ex = __expf(e - mx);
    float sm = ex;
#pragma unroll
    for (int off = 1; off < 16; off <<= 1) sm += __shfl_xor(sm, off);
    Aout[(size_t)b * 256 + t] = ex / sm;
  }
  if (Eout) Eout[(size_t)b * 256 + t] = e;
}

// ---------------- GNN combine: V += relu(A @ G) per batch ----------------
__global__ __launch_bounds__(256) void combine_kernel(const float* __restrict__ Aws,
                                                      const float* __restrict__ G,
                                                      float* __restrict__ V32,
                                                      float* __restrict__ Vout) {
  __shared__ float Gs[16 * 772];
  __shared__ float As[256];
  int b = blockIdx.x, t = threadIdx.x;
#pragma unroll
  for (int r = 0; r < 12; ++r) {
    int idx = t + 256 * r;
    int row = idx / 192, c4 = idx % 192;
    *(f32x4*)&Gs[row * 772 + c4 * 4] = *(const f32x4*)&G[(size_t)(b * 16 + row) * 768 + c4 * 4];
  }
  As[t] = Aws[(size_t)b * 256 + t];
  __syncthreads();
#pragma unroll
  for (int m = 0; m < 3; ++m) {
    int d = t + m * 256;
    float gv[16];
#pragma unroll
    for (int j = 0; j < 16; ++j) gv[j] = Gs[j * 772 + d];
#pragma unroll
    for (int i = 0; i < 16; ++i) {
      float msg = 0.f;
#pragma unroll
      for (int j = 0; j < 16; ++j) msg += As[i * 16 + j] * gv[j];
      size_t idx = (size_t)b * 12288 + (size_t)i * 768 + d;
      float v = V32[idx] + fmaxf(msg, 0.f);
      V32[idx] = v;
      if (Vout) Vout[idx] = v;
    }
  }
}

extern "C" void kernel_launch(void* const* d_in, const int* in_sizes, int n_in,
                              void* d_out, int out_size, void* d_ws, size_t ws_size,
                              hipStream_t stream) {
  const float* w    = (const float*)d_in[0];   // [256,77,768]
  const int*   mask = (const int*)d_in[1];     // [256,77]
  const float* nq   = (const float*)d_in[2];   // [1,16,768]
  const float* Wq   = (const float*)d_in[3];
  const float* bq   = (const float*)d_in[4];
  const float* Wk   = (const float*)d_in[5];
  const float* bk   = (const float*)d_in[6];
  const float* Wv   = (const float*)d_in[7];
  const float* bv   = (const float*)d_in[8];
  const float* We1  = (const float*)d_in[9];   // [1536,512]
  const float* be1  = (const float*)d_in[10];
  const float* We2  = (const float*)d_in[11];  // [512,1]
  const float* be2  = (const float*)d_in[12];
  const float* gate = (const float*)d_in[13];
  const float* Wg   = (const float*)d_in[14];  // [2,768,768]
  const float* bg   = (const float*)d_in[15];  // [2,768]

  // workspace (~79.7 MB)
  float* ws  = (float*)d_ws;
  float* Qb  = ws;                  // 12,288 f
  float* V32 = Qb + 12288;          // 3,145,728 f
  float* Aws = V32 + 3145728;       // 65,536 f
  u16* WkvT  = (u16*)(Aws + 65536); // [1536][768] bf16
  u16* We1T  = WkvT + 1179648;      // [1024][768] bf16
  u16* WgT   = We1T + 786432;       // [2][768][768] bf16
  u16* w16   = WgT + 1179648;       // 15,138,816 u16 (w as bf16; dead after gemmV)
  // regionB: Kt/Vt bf16 [19712][768] (alive gemmK..pv) OR HIJ+G fp32 (after pv)
  u16* KVt   = w16 + 15138816;      // 15,138,816 u16
  float* HIJ = (float*)KVt;         // 4,194,304 f
  float* Gws = HIJ + 4194304;       // 3,145,728 f

  float* out  = (float*)d_out;
  float* Sout = out;                       // [256,77,16]
  float* Vout = out + 315392;              // [256,16,768]
  float* Eout = out + 315392 + 3145728;    // [256,16,16]

  dim3 blk(256);

  // weights -> bf16 transposed [n][k]; w -> bf16
  tcast_all<<<dim3(24, 24, 6), blk, 0, stream>>>(Wk, Wv, We1, Wg, WkvT, We1T, WgT);
  wcast_k<<<7392, blk, 0, stream>>>(w, w16, 1892352);

  // Q = nq @ Wq + bq (fp32)
  q_kernel<<<48, blk, 0, stream>>>(nq, Wq, bq, Qb);

  // Kt = w16 @ WkT + bk (bf16) ; scores+softmax -> S
  gemm16<<<dim3(154, 6), blk, 0, stream>>>(w16, WkvT, bk, KVt, 768, 768);
  score_kernel<<<256, blk, 0, stream>>>(Qb, KVt, mask, Sout);

  // Vt = w16 @ WvT + bv (same buffer) ; V = S^T Vt, gate blend
  gemm16<<<dim3(154, 6), blk, 0, stream>>>(w16, WkvT + 589824, bv, KVt, 768, 768);
  pv_kernel<<<256, blk, 0, stream>>>(Sout, KVt, nq, gate, V32);

  // pre-GNN edge logits -> A   (HIJ = [V@We1_hi | V@We1_hj], fp32, no bias)
  gemm_bt<<<dim3(32, 8), blk, 0, stream>>>(V32, We1T, nullptr, nullptr, 0, HIJ, 1024, 768);
  edge_kernel<<<256, blk, 0, stream>>>(HIJ, be1, We2, be2, Aws, (float*)nullptr);

  // GNN layer 0
  gemm_bt<<<dim3(32, 6), blk, 0, stream>>>(V32, WgT, bg, bg, 768, Gws, 768, 768);
  combine_kernel<<<256, blk, 0, stream>>>(Aws, Gws, V32, (float*)nullptr);

  // GNN layer 1 (writes final V to d_out)
  gemm_bt<<<dim3(32, 6), blk, 0, stream>>>(V32, WgT + 589824, bg + 768, bg + 768, 768, Gws, 768, 768);
  combine_kernel<<<256, blk, 0, stream>>>(Aws, Gws, V32, Vout);

  // post-GNN edge logits -> E
  gemm_bt<<<dim3(32, 8), blk, 0, stream>>>(V32, We1T, nullptr, nullptr, 0, HIJ, 1024, 768);
  edge_kernel<<<256, blk, 0, stream>>>(HIJ, be1, We2, be2, (float*)nullptr, Eout);
}

// Round 5
// 440.674 us; speedup vs baseline: 2.9589x; 1.2548x over previous
//
#include <hip/hip_runtime.h>

typedef unsigned short u16;
typedef __attribute__((ext_vector_type(8))) short short8;
typedef __attribute__((ext_vector_type(4))) float f32x4;

#define DEV static __device__ __forceinline__

DEV float bf2f(u16 u) { return __uint_as_float(((unsigned)u) << 16); }
DEV u16 f2bf(float f) {
  unsigned u = __float_as_uint(f);
  return (u16)((u + 0x7fffu + ((u >> 16) & 1u)) >> 16);
}

// async global->LDS, 16B per lane; LDS dest = wave-uniform base + lane*16
DEV void cp16(void* lds, const void* g) {
  __builtin_amdgcn_global_load_lds(
      (const __attribute__((address_space(1))) unsigned int*)g,
      (__attribute__((address_space(3))) unsigned int*)lds, 16, 0, 0);
}

// dims: B=256, N=77, D=768, K=16, Dn=768, HID=512, L=2

// ---------------- cast fp32 -> bf16, 8 elems/thread ----------------
__global__ __launch_bounds__(256) void wcast_k(const float* __restrict__ src,
                                               u16* __restrict__ dst, int n8) {
  int i = blockIdx.x * 256 + threadIdx.x;
  if (i >= n8) return;
  f32x4 a = *(const f32x4*)&src[(size_t)i * 8];
  f32x4 b = *(const f32x4*)&src[(size_t)i * 8 + 4];
  short8 o;
#pragma unroll
  for (int e = 0; e < 4; ++e) { o[e] = (short)f2bf(a[e]); o[e + 4] = (short)f2bf(b[e]); }
  *(short8*)&dst[(size_t)i * 8] = o;
}

// ---------------- all weight transposes+casts in one launch ----------------
__global__ __launch_bounds__(256) void tcast_all(const float* __restrict__ Wk,
                                                 const float* __restrict__ Wv,
                                                 const float* __restrict__ We1,
                                                 const float* __restrict__ Wg,
                                                 u16* __restrict__ WkvT,
                                                 u16* __restrict__ We1T,
                                                 u16* __restrict__ WgT) {
  __shared__ float tile[32][33];
  const float* src; u16* dst; int C;
  switch (blockIdx.z) {
    case 0: src = Wk;           dst = WkvT;          C = 768; break;
    case 1: src = Wv;           dst = WkvT + 589824; C = 768; break;
    case 2: src = We1;          dst = We1T;          C = 512; break;
    case 3: src = We1 + 393216; dst = We1T + 393216; C = 512; break;
    case 4: src = Wg;           dst = WgT;           C = 768; break;
    default: src = Wg + 589824; dst = WgT + 589824;  C = 768; break;
  }
  int r0 = blockIdx.y * 32, c0 = blockIdx.x * 32;
  if (c0 >= C) return;
  int tr = threadIdx.x >> 5, tc = threadIdx.x & 31;
#pragma unroll
  for (int rr = 0; rr < 4; ++rr)
    tile[tr + rr * 8][tc] = src[(size_t)(r0 + tr + rr * 8) * C + c0 + tc];
  __syncthreads();
#pragma unroll
  for (int rr = 0; rr < 4; ++rr)
    dst[(size_t)(c0 + tr + rr * 8) * 768 + r0 + tc] = f2bf(tile[tc][tr + rr * 8]);
}

// ---------------- Q = node_queries @ Wq + bq -> bf16 [16][768] ----------------
__global__ __launch_bounds__(256) void q_kernel(const float* __restrict__ nq,
                                                const float* __restrict__ Wq,
                                                const float* __restrict__ bq,
                                                u16* __restrict__ Qb16) {
  int gid = blockIdx.x * 256 + threadIdx.x;  // 0..12287
  int k = gid / 768, d = gid % 768;
  const float* nr = nq + k * 768;
  float s0 = 0.f, s1 = 0.f, s2 = 0.f, s3 = 0.f;
  for (int c = 0; c < 768; c += 4) {
    s0 += nr[c + 0] * Wq[(size_t)(c + 0) * 768 + d];
    s1 += nr[c + 1] * Wq[(size_t)(c + 1) * 768 + d];
    s2 += nr[c + 2] * Wq[(size_t)(c + 2) * 768 + d];
    s3 += nr[c + 3] * Wq[(size_t)(c + 3) * 768 + d];
  }
  Qb16[gid] = f2bf(bq[d] + ((s0 + s1) + (s2 + s3)));
}

// ---------------- pure-bf16 MFMA GEMM, async staging, swizzled LDS ----------------
// A bf16 [M][K], BT bf16 [N][K], C bf16 [M][N] = A@BT^T + bias(n).
// Grouped raster (8 m-tiles/group). LDS chunk swizzle: chunk ^= (row>>1)&3.
// grid = mt*nt blocks, 256 threads.
__global__ __launch_bounds__(256) void gemm16(const u16* __restrict__ A,
                                              const u16* __restrict__ BT,
                                              const float* __restrict__ bias0,
                                              const float* __restrict__ bias1, int Nh,
                                              u16* __restrict__ C, int N, int K,
                                              int mt, int nt) {
  __shared__ u16 As[128 * 32];
  __shared__ u16 Bs[128 * 32];
  int gid = blockIdx.x;
  int per = 8 * nt;
  int group = gid / per;
  int within = gid - group * per;
  int gsz = mt - group * 8; if (gsz > 8) gsz = 8;
  int mi = group * 8 + within % gsz;
  int ni = within / gsz;
  int m0 = mi * 128, n0 = ni * 128;
  int t = threadIdx.x;
  int wave = t >> 6, lane = t & 63, l16 = lane & 15, quad = lane >> 4;
  int wrow = (wave >> 1) * 64, wcol = (wave & 1) * 64;
  // staging coords (two 16-row cp16 per wave per matrix)
  int r1 = wave * 32 + (lane >> 2);
  int r2 = r1 + 16;
  int cslot = lane & 3;
  int cg1 = (cslot ^ ((r1 >> 1) & 3)) * 8;
  int cg2 = (cslot ^ ((r2 >> 1) & 3)) * 8;

  f32x4 zero4 = {0.f, 0.f, 0.f, 0.f};
  f32x4 acc[4][4];
#pragma unroll
  for (int i = 0; i < 4; ++i)
#pragma unroll
    for (int j = 0; j < 4; ++j) acc[i][j] = zero4;

  for (int k0 = 0; k0 < K; k0 += 32) {
    cp16(&As[(wave * 32) * 32],      A + (size_t)(m0 + r1) * K + k0 + cg1);
    cp16(&As[(wave * 32 + 16) * 32], A + (size_t)(m0 + r2) * K + k0 + cg2);
    cp16(&Bs[(wave * 32) * 32],      BT + (size_t)(n0 + r1) * K + k0 + cg1);
    cp16(&Bs[(wave * 32 + 16) * 32], BT + (size_t)(n0 + r2) * K + k0 + cg2);
    __syncthreads();
    short8 fa[4], fb[4];
#pragma unroll
    for (int i = 0; i < 4; ++i) {
      int R = wrow + i * 16 + l16;
      fa[i] = *(const short8*)&As[R * 32 + (quad ^ ((R >> 1) & 3)) * 8];
    }
#pragma unroll
    for (int j = 0; j < 4; ++j) {
      int R = wcol + j * 16 + l16;
      fb[j] = *(const short8*)&Bs[R * 32 + (quad ^ ((R >> 1) & 3)) * 8];
    }
#pragma unroll
    for (int i = 0; i < 4; ++i)
#pragma unroll
      for (int j = 0; j < 4; ++j)
        acc[i][j] = __builtin_amdgcn_mfma_f32_16x16x32_bf16(fa[i], fb[j], acc[i][j], 0, 0, 0);
    __syncthreads();
  }

#pragma unroll
  for (int j = 0; j < 4; ++j) {
    int n = n0 + wcol + j * 16 + l16;
    float bv = 0.f;
    if (bias0) bv = (n < Nh) ? bias0[n] : bias1[n - Nh];
#pragma unroll
    for (int i = 0; i < 4; ++i)
#pragma unroll
      for (int r = 0; r < 4; ++r) {
        int m = m0 + wrow + i * 16 + quad * 4 + r;
        C[(size_t)m * N + n] = f2bf(acc[i][j][r] + bv);
      }
  }
}

// ---------------- scores via MFMA + fused mask/softmax ----------------
// S[row][k] = softmax_k( scale * Kt[row,:]·Q[k,:] , mask[row] ), row = b*77+n.
// grid 308 (64 rows each), block 256. Kt bf16 stride 768, Q bf16 [16][768].
__global__ __launch_bounds__(256) void score_mfma(const u16* __restrict__ Qb16,
                                                  const u16* __restrict__ Kt,
                                                  const int* __restrict__ mask,
                                                  float* __restrict__ Sout) {
  __shared__ u16 Qs[16 * 776];  // pad 776: 2-way banks on fb reads
  __shared__ u16 As[64 * 32];   // swizzled like gemm16
  int t = threadIdx.x, wave = t >> 6, lane = t & 63, l16 = lane & 15, quad = lane >> 4;
  int m0 = blockIdx.x * 64;
  // stage Q once: 16x768
#pragma unroll
  for (int r = 0; r < 6; ++r) {
    int idx = t + 256 * r;
    int row = idx / 96, c8 = idx % 96;
    *(short8*)&Qs[row * 776 + c8 * 8] = *(const short8*)&Qb16[row * 768 + c8 * 8];
  }
  int r1 = wave * 16 + (lane >> 2);
  int cg1 = ((lane & 3) ^ ((r1 >> 1) & 3)) * 8;
  f32x4 acc = {0.f, 0.f, 0.f, 0.f};
  __syncthreads();
  for (int k0 = 0; k0 < 768; k0 += 32) {
    cp16(&As[(wave * 16) * 32], Kt + (size_t)(m0 + r1) * 768 + k0 + cg1);
    __syncthreads();
    int R = wave * 16 + l16;
    short8 fa = *(const short8*)&As[R * 32 + (quad ^ ((R >> 1) & 3)) * 8];
    short8 fb = *(const short8*)&Qs[l16 * 776 + k0 + quad * 8];
    acc = __builtin_amdgcn_mfma_f32_16x16x32_bf16(fa, fb, acc, 0, 0, 0);
    __syncthreads();
  }
  const float scale = 0.1020620726159658f;  // (768/8)^-0.5
#pragma unroll
  for (int r = 0; r < 4; ++r) {
    int row = m0 + wave * 16 + quad * 4 + r;
    float s = acc[r] * scale;
    if (mask[row] == 0) s = -3.402823466e38f;  // finfo(f32).min
    float mx = s;
#pragma unroll
    for (int off = 1; off < 16; off <<= 1) mx = fmaxf(mx, __shfl_xor(mx, off));
    float e = __expf(s - mx);
    float sm = e;
#pragma unroll
    for (int off = 1; off < 16; off <<= 1) sm += __shfl_xor(sm, off);
    Sout[(size_t)row * 16 + l16] = e / sm;
  }
}

// ---------------- PV: V = S^T @ Vt, gate blend. grid (256 batches, 3 d-chunks) ----------------
__global__ __launch_bounds__(256) void pv_kernel(const float* __restrict__ Sg,
                                                 const u16* __restrict__ Vt,
                                                 const float* __restrict__ nq,
                                                 const float* __restrict__ gatep,
                                                 float* __restrict__ V32,
                                                 u16* __restrict__ V16) {
  __shared__ float Ss[1232];
  int b = blockIdx.x, t = threadIdx.x;
  int d = blockIdx.y * 256 + t;
#pragma unroll
  for (int r = 0; r < 5; ++r) {
    int idx = t + 256 * r;
    if (idx < 1232) Ss[idx] = Sg[(size_t)b * 1232 + idx];
  }
  __syncthreads();
  float a[16];
#pragma unroll
  for (int k = 0; k < 16; ++k) a[k] = 0.f;
  const u16* vt = Vt + (size_t)b * 77 * 768;
  for (int n = 0; n < 77; ++n) {
    float g = bf2f(vt[(size_t)n * 768 + d]);
    const float* sr = &Ss[n * 16];
#pragma unroll
    for (int k = 0; k < 16; ++k) a[k] += sr[k] * g;
  }
  float gv = gatep[0];
  float gate = 1.f / (1.f + __expf(-gv));
  float og = 1.f - gate;
#pragma unroll
  for (int k = 0; k < 16; ++k) {
    float val = og * a[k] + gate * nq[k * 768 + d];
    size_t idx = (size_t)b * 12288 + (size_t)k * 768 + d;
    V32[idx] = val;
    V16[idx] = f2bf(val);
  }
}

// ---------------- edge logits (+softmax) per batch; HIJ bf16 ----------------
__global__ __launch_bounds__(256) void edge_kernel(const u16* __restrict__ HIJ,
                                                   const float* __restrict__ be1,
                                                   const float* __restrict__ We2,
                                                   const float* __restrict__ be2v,
                                                   float* __restrict__ Aout,
                                                   float* __restrict__ Eout) {
  __shared__ float hiS[16 * 260];
  __shared__ float hjS[16 * 260];
  __shared__ float be1s[512];
  __shared__ float w2s[512];
  int b = blockIdx.x, t = threadIdx.x;
  be1s[t] = be1[t]; be1s[t + 256] = be1[t + 256];
  w2s[t] = We2[t];  w2s[t + 256] = We2[t + 256];

  int i = t >> 4, jj = t & 15;
  float e = 0.f;
  for (int half = 0; half < 2; ++half) {
    __syncthreads();
#pragma unroll
    for (int r = 0; r < 2; ++r) {
      int idx = t + 256 * r;          // 512 short8 chunks per half
      int row = idx >> 5, c8 = idx & 31;
      const u16* src = &HIJ[(size_t)(b * 16 + row) * 1024 + half * 256 + c8 * 8];
      short8 hv = *(const short8*)src;
      short8 jv = *(const short8*)(src + 512);
      f32x4 l0, l1, m0v, m1v;
#pragma unroll
      for (int ee = 0; ee < 4; ++ee) {
        l0[ee] = bf2f((u16)hv[ee]); l1[ee] = bf2f((u16)hv[ee + 4]);
        m0v[ee] = bf2f((u16)jv[ee]); m1v[ee] = bf2f((u16)jv[ee + 4]);
      }
      *(f32x4*)&hiS[row * 260 + c8 * 8] = l0;
      *(f32x4*)&hiS[row * 260 + c8 * 8 + 4] = l1;
      *(f32x4*)&hjS[row * 260 + c8 * 8] = m0v;
      *(f32x4*)&hjS[row * 260 + c8 * 8 + 4] = m1v;
    }
    __syncthreads();
    const float* hi = &hiS[i * 260];
    const float* hj = &hjS[jj * 260];
    const float* b1 = &be1s[half * 256];
    const float* w2 = &w2s[half * 256];
#pragma unroll 2
    for (int h4 = 0; h4 < 64; ++h4) {
      f32x4 hv = *(const f32x4*)&hi[h4 * 4];
      f32x4 jv = *(const f32x4*)&hj[h4 * 4];
      f32x4 bv = *(const f32x4*)&b1[h4 * 4];
      f32x4 wv = *(const f32x4*)&w2[h4 * 4];
#pragma unroll
      for (int ee = 0; ee < 4; ++ee)
        e += fmaxf(hv[ee] + jv[ee] + bv[ee], 0.f) * wv[ee];
    }
  }
  e += be2v[0];

  if (Aout) {
    float mx = e;
#pragma unroll
    for (int off = 1; off < 16; off <<= 1) mx = fmaxf(mx, __shfl_xor(mx, off));
    float ex = __expf(e - mx);
    float sm = ex;
#pragma unroll
    for (int off = 1; off < 16; off <<= 1) sm += __shfl_xor(sm, off);
    Aout[(size_t)b * 256 + t] = ex / sm;
  }
  if (Eout) Eout[(size_t)b * 256 + t] = e;
}

// ---------------- GNN combine: V += relu(A @ G); G bf16 ----------------
__global__ __launch_bounds__(256) void combine_kernel(const float* __restrict__ Aws,
                                                      const u16* __restrict__ G,
                                                      float* __restrict__ V32,
                                                      u16* __restrict__ V16,
                                                      float* __restrict__ Vout) {
  __shared__ float Gs[16 * 772];
  __shared__ float As[256];
  int b = blockIdx.x, t = threadIdx.x;
#pragma unroll
  for (int r = 0; r < 6; ++r) {
    int idx = t + 256 * r;
    int row = idx / 96, c8 = idx % 96;
    short8 gv8 = *(const short8*)&G[(size_t)(b * 16 + row) * 768 + c8 * 8];
    f32x4 l0, l1;
#pragma unroll
    for (int ee = 0; ee < 4; ++ee) { l0[ee] = bf2f((u16)gv8[ee]); l1[ee] = bf2f((u16)gv8[ee + 4]); }
    *(f32x4*)&Gs[row * 772 + c8 * 8] = l0;
    *(f32x4*)&Gs[row * 772 + c8 * 8 + 4] = l1;
  }
  As[t] = Aws[(size_t)b * 256 + t];
  __syncthreads();
#pragma unroll
  for (int m = 0; m < 3; ++m) {
    int d = t + m * 256;
    float gv[16];
#pragma unroll
    for (int j = 0; j < 16; ++j) gv[j] = Gs[j * 772 + d];
#pragma unroll
    for (int i = 0; i < 16; ++i) {
      float msg = 0.f;
#pragma unroll
      for (int j = 0; j < 16; ++j) msg += As[i * 16 + j] * gv[j];
      size_t idx = (size_t)b * 12288 + (size_t)i * 768 + d;
      float v = V32[idx] + fmaxf(msg, 0.f);
      V32[idx] = v;
      V16[idx] = f2bf(v);
      if (Vout) Vout[idx] = v;
    }
  }
}

extern "C" void kernel_launch(void* const* d_in, const int* in_sizes, int n_in,
                              void* d_out, int out_size, void* d_ws, size_t ws_size,
                              hipStream_t stream) {
  const float* w    = (const float*)d_in[0];   // [256,77,768]
  const int*   mask = (const int*)d_in[1];     // [256,77]
  const float* nq   = (const float*)d_in[2];   // [1,16,768]
  const float* Wq   = (const float*)d_in[3];
  const float* bq   = (const float*)d_in[4];
  const float* Wk   = (const float*)d_in[5];
  const float* bk   = (const float*)d_in[6];
  const float* Wv   = (const float*)d_in[7];
  const float* bv   = (const float*)d_in[8];
  const float* We1  = (const float*)d_in[9];   // [1536,512]
  const float* be1  = (const float*)d_in[10];
  const float* We2  = (const float*)d_in[11];  // [512,1]
  const float* be2  = (const float*)d_in[12];
  const float* gate = (const float*)d_in[13];
  const float* Wg   = (const float*)d_in[14];  // [2,768,768]
  const float* bg   = (const float*)d_in[15];  // [2,768]

  // workspace (~86 MB)
  float* ws   = (float*)d_ws;
  float* V32  = ws;                    // 3,145,728 f
  float* Aws  = V32 + 3145728;         // 65,536 f
  u16* Qb16   = (u16*)(Aws + 65536);   // 12,288 u16
  u16* WkvT   = Qb16 + 12288;          // 1,179,648
  u16* We1T   = WkvT + 1179648;        // 786,432
  u16* WgT    = We1T + 786432;         // 1,179,648
  u16* V16    = WgT + 1179648;         // 3,145,728
  u16* w16    = V16 + 3145728;         // 15,138,816 (dead after V-gemm)
  u16* KVt    = w16 + 15138816;        // 15,138,816 (Kt then Vt; dead after pv)
  // unions into dead w16 region (after pv):
  u16* HIJ    = w16;                   // 4,194,304 u16
  u16* Gws    = w16 + 4194304;         // 3,145,728 u16

  float* out  = (float*)d_out;
  float* Sout = out;                       // [256,77,16]
  float* Vout = out + 315392;              // [256,16,768]
  float* Eout = out + 315392 + 3145728;    // [256,16,16]

  dim3 blk(256);

  // weights -> bf16 transposed [n][k]; w -> bf16; Q -> bf16
  tcast_all<<<dim3(24, 24, 6), blk, 0, stream>>>(Wk, Wv, We1, Wg, WkvT, We1T, WgT);
  wcast_k<<<7392, blk, 0, stream>>>(w, w16, 1892352);
  q_kernel<<<48, blk, 0, stream>>>(nq, Wq, bq, Qb16);

  // Kt = w16 @ WkT + bk ; scores+softmax -> Sout
  gemm16<<<924, blk, 0, stream>>>(w16, WkvT, bk, nullptr, 768, KVt, 768, 768, 154, 6);
  score_mfma<<<308, blk, 0, stream>>>(Qb16, KVt, mask, Sout);

  // Vt = w16 @ WvT + bv (same buffer) ; V = S^T Vt + gate blend
  gemm16<<<924, blk, 0, stream>>>(w16, WkvT + 589824, bv, nullptr, 768, KVt, 768, 768, 154, 6);
  pv_kernel<<<dim3(256, 3), blk, 0, stream>>>(Sout, KVt, nq, gate, V32, V16);

  // pre-GNN edge logits -> A
  gemm16<<<256, blk, 0, stream>>>(V16, We1T, nullptr, nullptr, 0, HIJ, 1024, 768, 32, 8);
  edge_kernel<<<256, blk, 0, stream>>>(HIJ, be1, We2, be2, Aws, (float*)nullptr);

  // GNN layer 0
  gemm16<<<192, blk, 0, stream>>>(V16, WgT, bg, nullptr, 768, Gws, 768, 768, 32, 6);
  combine_kernel<<<256, blk, 0, stream>>>(Aws, Gws, V32, V16, (float*)nullptr);

  // GNN layer 1 (writes final V to d_out)
  gemm16<<<192, blk, 0, stream>>>(V16, WgT + 589824, bg + 768, nullptr, 768, Gws, 768, 768, 32, 6);
  combine_kernel<<<256, blk, 0, stream>>>(Aws, Gws, V32, V16, Vout);

  // post-GNN edge logits -> E
  gemm16<<<256, blk, 0, stream>>>(V16, We1T, nullptr, nullptr, 0, HIJ, 1024, 768, 32, 8);
  edge_kernel<<<256, blk, 0, stream>>>(HIJ, be1, We2, be2, (float*)nullptr, Eout);
}

// Round 6
// 426.161 us; speedup vs baseline: 3.0597x; 1.0341x over previous
//
#include <hip/hip_runtime.h>

typedef unsigned short u16;
typedef __attribute__((ext_vector_type(8))) short short8;
typedef __attribute__((ext_vector_type(4))) float f32x4;

#define DEV static __device__ __forceinline__

DEV float bf2f(u16 u) { return __uint_as_float(((unsigned)u) << 16); }
DEV u16 f2bf(float f) {
  unsigned u = __float_as_uint(f);
  return (u16)((u + 0x7fffu + ((u >> 16) & 1u)) >> 16);
}

// async global->LDS, 16B per lane; LDS dest = wave-uniform base + lane*16
DEV void cp16(void* lds, const void* g) {
  __builtin_amdgcn_global_load_lds(
      (const __attribute__((address_space(1))) unsigned int*)g,
      (__attribute__((address_space(3))) unsigned int*)lds, 16, 0, 0);
}

// dims: B=256, N=77, D=768, K=16, Dn=768, HID=512, L=2

// ---------------- cast fp32 -> bf16, 8 elems/thread ----------------
__global__ __launch_bounds__(256) void wcast_k(const float* __restrict__ src,
                                               u16* __restrict__ dst, int n8) {
  int i = blockIdx.x * 256 + threadIdx.x;
  if (i >= n8) return;
  f32x4 a = *(const f32x4*)&src[(size_t)i * 8];
  f32x4 b = *(const f32x4*)&src[(size_t)i * 8 + 4];
  short8 o;
#pragma unroll
  for (int e = 0; e < 4; ++e) { o[e] = (short)f2bf(a[e]); o[e + 4] = (short)f2bf(b[e]); }
  *(short8*)&dst[(size_t)i * 8] = o;
}

// ---------------- all weight transposes+casts in one launch ----------------
__global__ __launch_bounds__(256) void tcast_all(const float* __restrict__ Wk,
                                                 const float* __restrict__ Wv,
                                                 const float* __restrict__ We1,
                                                 const float* __restrict__ Wg,
                                                 u16* __restrict__ WkvT,
                                                 u16* __restrict__ We1T,
                                                 u16* __restrict__ WgT) {
  __shared__ float tile[32][33];
  const float* src; u16* dst; int C;
  switch (blockIdx.z) {
    case 0: src = Wk;           dst = WkvT;          C = 768; break;
    case 1: src = Wv;           dst = WkvT + 589824; C = 768; break;
    case 2: src = We1;          dst = We1T;          C = 512; break;
    case 3: src = We1 + 393216; dst = We1T + 393216; C = 512; break;
    case 4: src = Wg;           dst = WgT;           C = 768; break;
    default: src = Wg + 589824; dst = WgT + 589824;  C = 768; break;
  }
  int r0 = blockIdx.y * 32, c0 = blockIdx.x * 32;
  if (c0 >= C) return;
  int tr = threadIdx.x >> 5, tc = threadIdx.x & 31;
#pragma unroll
  for (int rr = 0; rr < 4; ++rr)
    tile[tr + rr * 8][tc] = src[(size_t)(r0 + tr + rr * 8) * C + c0 + tc];
  __syncthreads();
#pragma unroll
  for (int rr = 0; rr < 4; ++rr)
    dst[(size_t)(c0 + tr + rr * 8) * 768 + r0 + tc] = f2bf(tile[tc][tr + rr * 8]);
}

// ---------------- Q = node_queries @ Wq + bq -> bf16 [16][768] ----------------
__global__ __launch_bounds__(256) void q_kernel(const float* __restrict__ nq,
                                                const float* __restrict__ Wq,
                                                const float* __restrict__ bq,
                                                u16* __restrict__ Qb16) {
  int gid = blockIdx.x * 256 + threadIdx.x;  // 0..12287
  int k = gid / 768, d = gid % 768;
  const float* nr = nq + k * 768;
  float s0 = 0.f, s1 = 0.f, s2 = 0.f, s3 = 0.f;
  for (int c = 0; c < 768; c += 4) {
    s0 += nr[c + 0] * Wq[(size_t)(c + 0) * 768 + d];
    s1 += nr[c + 1] * Wq[(size_t)(c + 1) * 768 + d];
    s2 += nr[c + 2] * Wq[(size_t)(c + 2) * 768 + d];
    s3 += nr[c + 3] * Wq[(size_t)(c + 3) * 768 + d];
  }
  Qb16[gid] = f2bf(bq[d] + ((s0 + s1) + (s2 + s3)));
}

// ---------------- big MFMA GEMM 128x128, async staging, swizzled LDS ----------------
__global__ __launch_bounds__(256) void gemm16(const u16* __restrict__ A,
                                              const u16* __restrict__ BT,
                                              const float* __restrict__ bias,
                                              u16* __restrict__ C, int N, int K,
                                              int mt, int nt) {
  __shared__ u16 As[128 * 32];
  __shared__ u16 Bs[128 * 32];
  int gid = blockIdx.x;
  int per = 8 * nt;
  int group = gid / per;
  int within = gid - group * per;
  int gsz = mt - group * 8; if (gsz > 8) gsz = 8;
  int mi = group * 8 + within % gsz;
  int ni = within / gsz;
  int m0 = mi * 128, n0 = ni * 128;
  int t = threadIdx.x;
  int wave = t >> 6, lane = t & 63, l16 = lane & 15, quad = lane >> 4;
  int wrow = (wave >> 1) * 64, wcol = (wave & 1) * 64;
  int r1 = wave * 32 + (lane >> 2);
  int r2 = r1 + 16;
  int cslot = lane & 3;
  int cg1 = (cslot ^ ((r1 >> 1) & 3)) * 8;
  int cg2 = (cslot ^ ((r2 >> 1) & 3)) * 8;

  f32x4 zero4 = {0.f, 0.f, 0.f, 0.f};
  f32x4 acc[4][4];
#pragma unroll
  for (int i = 0; i < 4; ++i)
#pragma unroll
    for (int j = 0; j < 4; ++j) acc[i][j] = zero4;

  for (int k0 = 0; k0 < K; k0 += 32) {
    cp16(&As[(wave * 32) * 32],      A + (size_t)(m0 + r1) * K + k0 + cg1);
    cp16(&As[(wave * 32 + 16) * 32], A + (size_t)(m0 + r2) * K + k0 + cg2);
    cp16(&Bs[(wave * 32) * 32],      BT + (size_t)(n0 + r1) * K + k0 + cg1);
    cp16(&Bs[(wave * 32 + 16) * 32], BT + (size_t)(n0 + r2) * K + k0 + cg2);
    __syncthreads();
    short8 fa[4], fb[4];
#pragma unroll
    for (int i = 0; i < 4; ++i) {
      int R = wrow + i * 16 + l16;
      fa[i] = *(const short8*)&As[R * 32 + (quad ^ ((R >> 1) & 3)) * 8];
    }
#pragma unroll
    for (int j = 0; j < 4; ++j) {
      int R = wcol + j * 16 + l16;
      fb[j] = *(const short8*)&Bs[R * 32 + (quad ^ ((R >> 1) & 3)) * 8];
    }
#pragma unroll
    for (int i = 0; i < 4; ++i)
#pragma unroll
      for (int j = 0; j < 4; ++j)
        acc[i][j] = __builtin_amdgcn_mfma_f32_16x16x32_bf16(fa[i], fb[j], acc[i][j], 0, 0, 0);
    __syncthreads();
  }

  // epilogue: row-contiguous store order (i,r outer, j inner) for write coalescing
  int narr[4]; float bvj[4];
#pragma unroll
  for (int j = 0; j < 4; ++j) {
    narr[j] = n0 + wcol + j * 16 + l16;
    bvj[j] = bias ? bias[narr[j]] : 0.f;
  }
#pragma unroll
  for (int i = 0; i < 4; ++i)
#pragma unroll
    for (int r = 0; r < 4; ++r) {
      size_t mrow = (size_t)(m0 + wrow + i * 16 + quad * 4 + r) * N;
#pragma unroll
      for (int j = 0; j < 4; ++j)
        C[mrow + narr[j]] = f2bf(acc[i][j][r] + bvj[j]);
    }
}

// ---------------- small MFMA GEMM 64x128, dual-output fused launch ----------------
// ni < ntA: C0[m][n]=A@BT0^T+bias0 (width N0); else C1/BT1/bias1 (width N1).
// grid = mt * (ntA+ntB); A is [M][K] bf16 (M multiple of 64).
__global__ __launch_bounds__(256) void gemm16s(const u16* __restrict__ A,
                                               const u16* __restrict__ BT0,
                                               const float* __restrict__ bias0,
                                               u16* __restrict__ C0, int N0, int ntA,
                                               const u16* __restrict__ BT1,
                                               const float* __restrict__ bias1,
                                               u16* __restrict__ C1, int N1, int ntB,
                                               int K) {
  __shared__ u16 As[64 * 32];
  __shared__ u16 Bs[128 * 32];
  int nt = ntA + ntB;
  int mi = blockIdx.x / nt, ni = blockIdx.x % nt;
  const u16* BT; const float* bias; u16* C; int N, n0;
  if (ni < ntA) { BT = BT0; bias = bias0; C = C0; N = N0; n0 = ni * 128; }
  else          { BT = BT1; bias = bias1; C = C1; N = N1; n0 = (ni - ntA) * 128; }
  int m0 = mi * 64;
  int t = threadIdx.x;
  int wave = t >> 6, lane = t & 63, l16 = lane & 15, quad = lane >> 4;
  // staging: A rows wave*16+(lane>>2); B rows wave*32+(lane>>2) and +16
  int ra = wave * 16 + (lane >> 2);
  int rb1 = wave * 32 + (lane >> 2);
  int rb2 = rb1 + 16;
  int cslot = lane & 3;
  int cga = (cslot ^ ((ra >> 1) & 3)) * 8;
  int cgb1 = (cslot ^ ((rb1 >> 1) & 3)) * 8;
  int cgb2 = (cslot ^ ((rb2 >> 1) & 3)) * 8;

  f32x4 zero4 = {0.f, 0.f, 0.f, 0.f};
  f32x4 acc[4][2];
#pragma unroll
  for (int i = 0; i < 4; ++i) { acc[i][0] = zero4; acc[i][1] = zero4; }

  for (int k0 = 0; k0 < K; k0 += 32) {
    cp16(&As[(wave * 16) * 32],      A + (size_t)(m0 + ra) * K + k0 + cga);
    cp16(&Bs[(wave * 32) * 32],      BT + (size_t)(n0 + rb1) * K + k0 + cgb1);
    cp16(&Bs[(wave * 32 + 16) * 32], BT + (size_t)(n0 + rb2) * K + k0 + cgb2);
    __syncthreads();
    short8 fa[4], fb[2];
#pragma unroll
    for (int i = 0; i < 4; ++i) {
      int R = i * 16 + l16;
      fa[i] = *(const short8*)&As[R * 32 + (quad ^ ((R >> 1) & 3)) * 8];
    }
#pragma unroll
    for (int j = 0; j < 2; ++j) {
      int R = wave * 32 + j * 16 + l16;
      fb[j] = *(const short8*)&Bs[R * 32 + (quad ^ ((R >> 1) & 3)) * 8];
    }
#pragma unroll
    for (int i = 0; i < 4; ++i)
#pragma unroll
      for (int j = 0; j < 2; ++j)
        acc[i][j] = __builtin_amdgcn_mfma_f32_16x16x32_bf16(fa[i], fb[j], acc[i][j], 0, 0, 0);
    __syncthreads();
  }

  int narr[2]; float bvj[2];
#pragma unroll
  for (int j = 0; j < 2; ++j) {
    narr[j] = n0 + wave * 32 + j * 16 + l16;
    bvj[j] = bias ? bias[narr[j]] : 0.f;
  }
#pragma unroll
  for (int i = 0; i < 4; ++i)
#pragma unroll
    for (int r = 0; r < 4; ++r) {
      size_t mrow = (size_t)(m0 + i * 16 + quad * 4 + r) * N;
#pragma unroll
      for (int j = 0; j < 2; ++j)
        C[mrow + narr[j]] = f2bf(acc[i][j][r] + bvj[j]);
    }
}

// ---------------- scores via MFMA, register-direct Kt, fused softmax ----------------
// grid 308 (64 rows), block 256. No in-loop barriers.
__global__ __launch_bounds__(256) void score_mfma(const u16* __restrict__ Qb16,
                                                  const u16* __restrict__ Kt,
                                                  const int* __restrict__ mask,
                                                  float* __restrict__ Sout) {
  __shared__ u16 Qs[16 * 776];
  int t = threadIdx.x, wave = t >> 6, lane = t & 63, l16 = lane & 15, quad = lane >> 4;
  int m0 = blockIdx.x * 64;
#pragma unroll
  for (int r = 0; r < 6; ++r) {
    int idx = t + 256 * r;
    int row = idx / 96, c8 = idx % 96;
    *(short8*)&Qs[row * 776 + c8 * 8] = *(const short8*)&Qb16[row * 768 + c8 * 8];
  }
  __syncthreads();
  int row = m0 + wave * 16 + l16;
  const u16* kp = Kt + (size_t)row * 768 + quad * 8;
  f32x4 acc = {0.f, 0.f, 0.f, 0.f};
#pragma unroll
  for (int it = 0; it < 24; ++it) {
    short8 fa = *(const short8*)(kp + it * 32);
    short8 fb = *(const short8*)&Qs[l16 * 776 + it * 32 + quad * 8];
    acc = __builtin_amdgcn_mfma_f32_16x16x32_bf16(fa, fb, acc, 0, 0, 0);
  }
  const float scale = 0.1020620726159658f;  // (768/8)^-0.5
#pragma unroll
  for (int r = 0; r < 4; ++r) {
    int orow = m0 + wave * 16 + quad * 4 + r;
    float s = acc[r] * scale;
    if (mask[orow] == 0) s = -3.402823466e38f;  // finfo(f32).min
    float mx = s;
#pragma unroll
    for (int off = 1; off < 16; off <<= 1) mx = fmaxf(mx, __shfl_xor(mx, off));
    float e = __expf(s - mx);
    float sm = e;
#pragma unroll
    for (int off = 1; off < 16; off <<= 1) sm += __shfl_xor(sm, off);
    Sout[(size_t)orow * 16 + l16] = e / sm;
  }
}

// ---------------- PV: V = S^T @ Vt, gate blend. grid (256, 3) ----------------
__global__ __launch_bounds__(256) void pv_kernel(const float* __restrict__ Sg,
                                                 const u16* __restrict__ Vt,
                                                 const float* __restrict__ nq,
                                                 const float* __restrict__ gatep,
                                                 float* __restrict__ V32,
                                                 u16* __restrict__ V16) {
  __shared__ float Ss[1232];
  int b = blockIdx.x, t = threadIdx.x;
  int d = blockIdx.y * 256 + t;
#pragma unroll
  for (int r = 0; r < 5; ++r) {
    int idx = t + 256 * r;
    if (idx < 1232) Ss[idx] = Sg[(size_t)b * 1232 + idx];
  }
  __syncthreads();
  float a[16];
#pragma unroll
  for (int k = 0; k < 16; ++k) a[k] = 0.f;
  const u16* vt = Vt + (size_t)b * 77 * 768;
  for (int n = 0; n < 77; ++n) {
    float g = bf2f(vt[(size_t)n * 768 + d]);
    const float* sr = &Ss[n * 16];
#pragma unroll
    for (int k = 0; k < 16; ++k) a[k] += sr[k] * g;
  }
  float gv = gatep[0];
  float gate = 1.f / (1.f + __expf(-gv));
  float og = 1.f - gate;
#pragma unroll
  for (int k = 0; k < 16; ++k) {
    float val = og * a[k] + gate * nq[k * 768 + d];
    size_t idx = (size_t)b * 12288 + (size_t)k * 768 + d;
    V32[idx] = val;
    V16[idx] = f2bf(val);
  }
}

// ---------------- edge logits (+softmax) per batch; HIJ bf16 ----------------
__global__ __launch_bounds__(256) void edge_kernel(const u16* __restrict__ HIJ,
                                                   const float* __restrict__ be1,
                                                   const float* __restrict__ We2,
                                                   const float* __restrict__ be2v,
                                                   float* __restrict__ Aout,
                                                   float* __restrict__ Eout) {
  __shared__ float hiS[16 * 260];
  __shared__ float hjS[16 * 260];
  __shared__ float be1s[512];
  __shared__ float w2s[512];
  int b = blockIdx.x, t = threadIdx.x;
  be1s[t] = be1[t]; be1s[t + 256] = be1[t + 256];
  w2s[t] = We2[t];  w2s[t + 256] = We2[t + 256];

  int i = t >> 4, jj = t & 15;
  float e = 0.f;
  for (int half = 0; half < 2; ++half) {
    __syncthreads();
#pragma unroll
    for (int r = 0; r < 2; ++r) {
      int idx = t + 256 * r;          // 512 short8 chunks per half
      int row = idx >> 5, c8 = idx & 31;
      const u16* src = &HIJ[(size_t)(b * 16 + row) * 1024 + half * 256 + c8 * 8];
      short8 hv = *(const short8*)src;
      short8 jv = *(const short8*)(src + 512);
      f32x4 l0, l1, m0v, m1v;
#pragma unroll
      for (int ee = 0; ee < 4; ++ee) {
        l0[ee] = bf2f((u16)hv[ee]); l1[ee] = bf2f((u16)hv[ee + 4]);
        m0v[ee] = bf2f((u16)jv[ee]); m1v[ee] = bf2f((u16)jv[ee + 4]);
      }
      *(f32x4*)&hiS[row * 260 + c8 * 8] = l0;
      *(f32x4*)&hiS[row * 260 + c8 * 8 + 4] = l1;
      *(f32x4*)&hjS[row * 260 + c8 * 8] = m0v;
      *(f32x4*)&hjS[row * 260 + c8 * 8 + 4] = m1v;
    }
    __syncthreads();
    const float* hi = &hiS[i * 260];
    const float* hj = &hjS[jj * 260];
    const float* b1 = &be1s[half * 256];
    const float* w2 = &w2s[half * 256];
#pragma unroll 2
    for (int h4 = 0; h4 < 64; ++h4) {
      f32x4 hv = *(const f32x4*)&hi[h4 * 4];
      f32x4 jv = *(const f32x4*)&hj[h4 * 4];
      f32x4 bv = *(const f32x4*)&b1[h4 * 4];
      f32x4 wv = *(const f32x4*)&w2[h4 * 4];
#pragma unroll
      for (int ee = 0; ee < 4; ++ee)
        e += fmaxf(hv[ee] + jv[ee] + bv[ee], 0.f) * wv[ee];
    }
  }
  e += be2v[0];

  if (Aout) {
    float mx = e;
#pragma unroll
    for (int off = 1; off < 16; off <<= 1) mx = fmaxf(mx, __shfl_xor(mx, off));
    float ex = __expf(e - mx);
    float sm = ex;
#pragma unroll
    for (int off = 1; off < 16; off <<= 1) sm += __shfl_xor(sm, off);
    Aout[(size_t)b * 256 + t] = ex / sm;
  }
  if (Eout) Eout[(size_t)b * 256 + t] = e;
}

// ---------------- GNN combine: V += relu(A @ G); G bf16 ----------------
__global__ __launch_bounds__(256) void combine_kernel(const float* __restrict__ Aws,
                                                      const u16* __restrict__ G,
                                                      float* __restrict__ V32,
                                                      u16* __restrict__ V16,
                                                      float* __restrict__ Vout) {
  __shared__ float Gs[16 * 772];
  __shared__ float As[256];
  int b = blockIdx.x, t = threadIdx.x;
#pragma unroll
  for (int r = 0; r < 6; ++r) {
    int idx = t + 256 * r;
    int row = idx / 96, c8 = idx % 96;
    short8 gv8 = *(const short8*)&G[(size_t)(b * 16 + row) * 768 + c8 * 8];
    f32x4 l0, l1;
#pragma unroll
    for (int ee = 0; ee < 4; ++ee) { l0[ee] = bf2f((u16)gv8[ee]); l1[ee] = bf2f((u16)gv8[ee + 4]); }
    *(f32x4*)&Gs[row * 772 + c8 * 8] = l0;
    *(f32x4*)&Gs[row * 772 + c8 * 8 + 4] = l1;
  }
  As[t] = Aws[(size_t)b * 256 + t];
  __syncthreads();
#pragma unroll
  for (int m = 0; m < 3; ++m) {
    int d = t + m * 256;
    float gv[16];
#pragma unroll
    for (int j = 0; j < 16; ++j) gv[j] = Gs[j * 772 + d];
#pragma unroll
    for (int i = 0; i < 16; ++i) {
      float msg = 0.f;
#pragma unroll
      for (int j = 0; j < 16; ++j) msg += As[i * 16 + j] * gv[j];
      size_t idx = (size_t)b * 12288 + (size_t)i * 768 + d;
      float v = V32[idx] + fmaxf(msg, 0.f);
      V32[idx] = v;
      V16[idx] = f2bf(v);
      if (Vout) Vout[idx] = v;
    }
  }
}

extern "C" void kernel_launch(void* const* d_in, const int* in_sizes, int n_in,
                              void* d_out, int out_size, void* d_ws, size_t ws_size,
                              hipStream_t stream) {
  const float* w    = (const float*)d_in[0];   // [256,77,768]
  const int*   mask = (const int*)d_in[1];     // [256,77]
  const float* nq   = (const float*)d_in[2];   // [1,16,768]
  const float* Wq   = (const float*)d_in[3];
  const float* bq   = (const float*)d_in[4];
  const float* Wk   = (const float*)d_in[5];
  const float* bk   = (const float*)d_in[6];
  const float* Wv   = (const float*)d_in[7];
  const float* bv   = (const float*)d_in[8];
  const float* We1  = (const float*)d_in[9];   // [1536,512]
  const float* be1  = (const float*)d_in[10];
  const float* We2  = (const float*)d_in[11];  // [512,1]
  const float* be2  = (const float*)d_in[12];
  const float* gate = (const float*)d_in[13];
  const float* Wg   = (const float*)d_in[14];  // [2,768,768]
  const float* bg   = (const float*)d_in[15];  // [2,768]

  // workspace (~86 MB)
  float* ws   = (float*)d_ws;
  float* V32  = ws;                    // 3,145,728 f
  float* Aws  = V32 + 3145728;         // 65,536 f
  u16* Qb16   = (u16*)(Aws + 65536);   // 12,288 u16
  u16* WkvT   = Qb16 + 12288;          // 1,179,648
  u16* We1T   = WkvT + 1179648;        // 786,432
  u16* WgT    = We1T + 786432;         // 1,179,648
  u16* V16    = WgT + 1179648;         // 3,145,728
  u16* w16    = V16 + 3145728;         // 15,138,816 (dead after V-gemm)
  u16* KVt    = w16 + 15138816;        // 15,138,816 (Kt then Vt; dead after pv)
  // unions into dead w16 region (after pv):
  u16* HIJ    = w16;                   // 4,194,304 u16
  u16* Gws    = w16 + 4194304;         // 3,145,728 u16

  float* out  = (float*)d_out;
  float* Sout = out;                       // [256,77,16]
  float* Vout = out + 315392;              // [256,16,768]
  float* Eout = out + 315392 + 3145728;    // [256,16,16]

  dim3 blk(256);

  // prep: weights -> bf16 [n][k]; w -> bf16; Q -> bf16
  tcast_all<<<dim3(24, 24, 6), blk, 0, stream>>>(Wk, Wv, We1, Wg, WkvT, We1T, WgT);
  wcast_k<<<7392, blk, 0, stream>>>(w, w16, 1892352);
  q_kernel<<<48, blk, 0, stream>>>(nq, Wq, bq, Qb16);

  // Kt = w16 @ WkT + bk ; scores+softmax -> Sout
  gemm16<<<924, blk, 0, stream>>>(w16, WkvT, bk, KVt, 768, 768, 154, 6);
  score_mfma<<<308, blk, 0, stream>>>(Qb16, KVt, mask, Sout);

  // Vt = w16 @ WvT + bv (same buffer) ; V = S^T Vt + gate blend
  gemm16<<<924, blk, 0, stream>>>(w16, WkvT + 589824, bv, KVt, 768, 768, 154, 6);
  pv_kernel<<<dim3(256, 3), blk, 0, stream>>>(Sout, KVt, nq, gate, V32, V16);

  // fused: pre-GNN edge gemm (HIJ, 8 n-tiles) + GNN layer-0 gemm (Gws, 6 n-tiles)
  gemm16s<<<896, blk, 0, stream>>>(V16, We1T, nullptr, HIJ, 1024, 8,
                                   WgT, bg, Gws, 768, 6, 768);
  edge_kernel<<<256, blk, 0, stream>>>(HIJ, be1, We2, be2, Aws, (float*)nullptr);
  combine_kernel<<<256, blk, 0, stream>>>(Aws, Gws, V32, V16, (float*)nullptr);

  // GNN layer 1
  gemm16s<<<384, blk, 0, stream>>>(V16, WgT + 589824, bg + 768, Gws, 768, 6,
                                   WgT + 589824, bg + 768, Gws, 768, 0, 768);
  combine_kernel<<<256, blk, 0, stream>>>(Aws, Gws, V32, V16, Vout);

  // post-GNN edge logits -> E
  gemm16s<<<512, blk, 0, stream>>>(V16, We1T, nullptr, HIJ, 1024, 8,
                                   We1T, nullptr, HIJ, 1024, 0, 768);
  edge_kernel<<<256, blk, 0, stream>>>(HIJ, be1, We2, be2, (float*)nullptr, Eout);
}

// Round 7
// 379.333 us; speedup vs baseline: 3.4374x; 1.1234x over previous
//
#include <hip/hip_runtime.h>

typedef unsigned short u16;
typedef __attribute__((ext_vector_type(8))) short short8;
typedef __attribute__((ext_vector_type(4))) float f32x4;

#define DEV static __device__ __forceinline__

DEV float bf2f(u16 u) { return __uint_as_float(((unsigned)u) << 16); }
DEV u16 f2bf(float f) {
  unsigned u = __float_as_uint(f);
  return (u16)((u + 0x7fffu + ((u >> 16) & 1u)) >> 16);
}

// async global->LDS, 16B per lane; LDS dest = wave-uniform base + lane*16
DEV void cp16(void* lds, const void* g) {
  __builtin_amdgcn_global_load_lds(
      (const __attribute__((address_space(1))) unsigned int*)g,
      (__attribute__((address_space(3))) unsigned int*)lds, 16, 0, 0);
}

// dims: B=256, N=77, D=768, K=16, Dn=768, HID=512, L=2

// ---------------- cast fp32 -> bf16, 8 elems/thread ----------------
__global__ __launch_bounds__(256) void wcast_k(const float* __restrict__ src,
                                               u16* __restrict__ dst, int n8) {
  int i = blockIdx.x * 256 + threadIdx.x;
  if (i >= n8) return;
  f32x4 a = *(const f32x4*)&src[(size_t)i * 8];
  f32x4 b = *(const f32x4*)&src[(size_t)i * 8 + 4];
  short8 o;
#pragma unroll
  for (int e = 0; e < 4; ++e) { o[e] = (short)f2bf(a[e]); o[e + 4] = (short)f2bf(b[e]); }
  *(short8*)&dst[(size_t)i * 8] = o;
}

// ---------------- all weight transposes+casts in one launch ----------------
__global__ __launch_bounds__(256) void tcast_all(const float* __restrict__ Wk,
                                                 const float* __restrict__ Wv,
                                                 const float* __restrict__ We1,
                                                 const float* __restrict__ Wg,
                                                 u16* __restrict__ WkvT,
                                                 u16* __restrict__ We1T,
                                                 u16* __restrict__ WgT) {
  __shared__ float tile[32][33];
  const float* src; u16* dst; int C;
  switch (blockIdx.z) {
    case 0: src = Wk;           dst = WkvT;          C = 768; break;
    case 1: src = Wv;           dst = WkvT + 589824; C = 768; break;
    case 2: src = We1;          dst = We1T;          C = 512; break;
    case 3: src = We1 + 393216; dst = We1T + 393216; C = 512; break;
    case 4: src = Wg;           dst = WgT;           C = 768; break;
    default: src = Wg + 589824; dst = WgT + 589824;  C = 768; break;
  }
  int r0 = blockIdx.y * 32, c0 = blockIdx.x * 32;
  if (c0 >= C) return;
  int tr = threadIdx.x >> 5, tc = threadIdx.x & 31;
#pragma unroll
  for (int rr = 0; rr < 4; ++rr)
    tile[tr + rr * 8][tc] = src[(size_t)(r0 + tr + rr * 8) * C + c0 + tc];
  __syncthreads();
#pragma unroll
  for (int rr = 0; rr < 4; ++rr)
    dst[(size_t)(c0 + tr + rr * 8) * 768 + r0 + tc] = f2bf(tile[tc][tr + rr * 8]);
}

// ---------------- Q projection, split-K stage 1 ----------------
// grid (48, 8): gid -> (k,d), blockIdx.y = 96-element K-slice.
__global__ __launch_bounds__(256) void q_part(const float* __restrict__ nq,
                                              const float* __restrict__ Wq,
                                              float* __restrict__ Qpart) {
  int gid = blockIdx.x * 256 + threadIdx.x;  // 0..12287
  int s = blockIdx.y;
  int k = gid / 768, d = gid % 768;
  const float* nr = nq + k * 768 + s * 96;
  const float* wp = Wq + (size_t)(s * 96) * 768 + d;
  float s0 = 0.f, s1 = 0.f, s2 = 0.f, s3 = 0.f;
#pragma unroll
  for (int c = 0; c < 96; c += 4) {
    s0 += nr[c + 0] * wp[(size_t)(c + 0) * 768];
    s1 += nr[c + 1] * wp[(size_t)(c + 1) * 768];
    s2 += nr[c + 2] * wp[(size_t)(c + 2) * 768];
    s3 += nr[c + 3] * wp[(size_t)(c + 3) * 768];
  }
  Qpart[(size_t)s * 12288 + gid] = (s0 + s1) + (s2 + s3);
}

// ---------------- Q projection, stage 2: reduce + bias + cast ----------------
__global__ __launch_bounds__(256) void q_reduce(const float* __restrict__ Qpart,
                                                const float* __restrict__ bq,
                                                u16* __restrict__ Qb16) {
  int gid = blockIdx.x * 256 + threadIdx.x;  // 0..12287
  int d = gid % 768;
  float s = bq[d];
#pragma unroll
  for (int i = 0; i < 8; ++i) s += Qpart[(size_t)i * 12288 + gid];
  Qb16[gid] = f2bf(s);
}

// ---------------- big MFMA GEMM 128x128, async staging, swizzled LDS ----------------
__global__ __launch_bounds__(256) void gemm16(const u16* __restrict__ A,
                                              const u16* __restrict__ BT,
                                              const float* __restrict__ bias,
                                              u16* __restrict__ C, int N, int K,
                                              int mt, int nt) {
  __shared__ u16 As[128 * 32];
  __shared__ u16 Bs[128 * 32];
  int gid = blockIdx.x;
  int per = 8 * nt;
  int group = gid / per;
  int within = gid - group * per;
  int gsz = mt - group * 8; if (gsz > 8) gsz = 8;
  int mi = group * 8 + within % gsz;
  int ni = within / gsz;
  int m0 = mi * 128, n0 = ni * 128;
  int t = threadIdx.x;
  int wave = t >> 6, lane = t & 63, l16 = lane & 15, quad = lane >> 4;
  int wrow = (wave >> 1) * 64, wcol = (wave & 1) * 64;
  int r1 = wave * 32 + (lane >> 2);
  int r2 = r1 + 16;
  int cslot = lane & 3;
  int cg1 = (cslot ^ ((r1 >> 1) & 3)) * 8;
  int cg2 = (cslot ^ ((r2 >> 1) & 3)) * 8;

  f32x4 zero4 = {0.f, 0.f, 0.f, 0.f};
  f32x4 acc[4][4];
#pragma unroll
  for (int i = 0; i < 4; ++i)
#pragma unroll
    for (int j = 0; j < 4; ++j) acc[i][j] = zero4;

  for (int k0 = 0; k0 < K; k0 += 32) {
    cp16(&As[(wave * 32) * 32],      A + (size_t)(m0 + r1) * K + k0 + cg1);
    cp16(&As[(wave * 32 + 16) * 32], A + (size_t)(m0 + r2) * K + k0 + cg2);
    cp16(&Bs[(wave * 32) * 32],      BT + (size_t)(n0 + r1) * K + k0 + cg1);
    cp16(&Bs[(wave * 32 + 16) * 32], BT + (size_t)(n0 + r2) * K + k0 + cg2);
    __syncthreads();
    short8 fa[4], fb[4];
#pragma unroll
    for (int i = 0; i < 4; ++i) {
      int R = wrow + i * 16 + l16;
      fa[i] = *(const short8*)&As[R * 32 + (quad ^ ((R >> 1) & 3)) * 8];
    }
#pragma unroll
    for (int j = 0; j < 4; ++j) {
      int R = wcol + j * 16 + l16;
      fb[j] = *(const short8*)&Bs[R * 32 + (quad ^ ((R >> 1) & 3)) * 8];
    }
#pragma unroll
    for (int i = 0; i < 4; ++i)
#pragma unroll
      for (int j = 0; j < 4; ++j)
        acc[i][j] = __builtin_amdgcn_mfma_f32_16x16x32_bf16(fa[i], fb[j], acc[i][j], 0, 0, 0);
    __syncthreads();
  }

  // epilogue: row-contiguous store order for write coalescing
  int narr[4]; float bvj[4];
#pragma unroll
  for (int j = 0; j < 4; ++j) {
    narr[j] = n0 + wcol + j * 16 + l16;
    bvj[j] = bias ? bias[narr[j]] : 0.f;
  }
#pragma unroll
  for (int i = 0; i < 4; ++i)
#pragma unroll
    for (int r = 0; r < 4; ++r) {
      size_t mrow = (size_t)(m0 + wrow + i * 16 + quad * 4 + r) * N;
#pragma unroll
      for (int j = 0; j < 4; ++j)
        C[mrow + narr[j]] = f2bf(acc[i][j][r] + bvj[j]);
    }
}

// ---------------- small MFMA GEMM 64x128, dual-output fused launch ----------------
__global__ __launch_bounds__(256) void gemm16s(const u16* __restrict__ A,
                                               const u16* __restrict__ BT0,
                                               const float* __restrict__ bias0,
                                               u16* __restrict__ C0, int N0, int ntA,
                                               const u16* __restrict__ BT1,
                                               const float* __restrict__ bias1,
                                               u16* __restrict__ C1, int N1, int ntB,
                                               int K) {
  __shared__ u16 As[64 * 32];
  __shared__ u16 Bs[128 * 32];
  int nt = ntA + ntB;
  int mi = blockIdx.x / nt, ni = blockIdx.x % nt;
  const u16* BT; const float* bias; u16* C; int N, n0;
  if (ni < ntA) { BT = BT0; bias = bias0; C = C0; N = N0; n0 = ni * 128; }
  else          { BT = BT1; bias = bias1; C = C1; N = N1; n0 = (ni - ntA) * 128; }
  int m0 = mi * 64;
  int t = threadIdx.x;
  int wave = t >> 6, lane = t & 63, l16 = lane & 15, quad = lane >> 4;
  int ra = wave * 16 + (lane >> 2);
  int rb1 = wave * 32 + (lane >> 2);
  int rb2 = rb1 + 16;
  int cslot = lane & 3;
  int cga = (cslot ^ ((ra >> 1) & 3)) * 8;
  int cgb1 = (cslot ^ ((rb1 >> 1) & 3)) * 8;
  int cgb2 = (cslot ^ ((rb2 >> 1) & 3)) * 8;

  f32x4 zero4 = {0.f, 0.f, 0.f, 0.f};
  f32x4 acc[4][2];
#pragma unroll
  for (int i = 0; i < 4; ++i) { acc[i][0] = zero4; acc[i][1] = zero4; }

  for (int k0 = 0; k0 < K; k0 += 32) {
    cp16(&As[(wave * 16) * 32],      A + (size_t)(m0 + ra) * K + k0 + cga);
    cp16(&Bs[(wave * 32) * 32],      BT + (size_t)(n0 + rb1) * K + k0 + cgb1);
    cp16(&Bs[(wave * 32 + 16) * 32], BT + (size_t)(n0 + rb2) * K + k0 + cgb2);
    __syncthreads();
    short8 fa[4], fb[2];
#pragma unroll
    for (int i = 0; i < 4; ++i) {
      int R = i * 16 + l16;
      fa[i] = *(const short8*)&As[R * 32 + (quad ^ ((R >> 1) & 3)) * 8];
    }
#pragma unroll
    for (int j = 0; j < 2; ++j) {
      int R = wave * 32 + j * 16 + l16;
      fb[j] = *(const short8*)&Bs[R * 32 + (quad ^ ((R >> 1) & 3)) * 8];
    }
#pragma unroll
    for (int i = 0; i < 4; ++i)
#pragma unroll
      for (int j = 0; j < 2; ++j)
        acc[i][j] = __builtin_amdgcn_mfma_f32_16x16x32_bf16(fa[i], fb[j], acc[i][j], 0, 0, 0);
    __syncthreads();
  }

  int narr[2]; float bvj[2];
#pragma unroll
  for (int j = 0; j < 2; ++j) {
    narr[j] = n0 + wave * 32 + j * 16 + l16;
    bvj[j] = bias ? bias[narr[j]] : 0.f;
  }
#pragma unroll
  for (int i = 0; i < 4; ++i)
#pragma unroll
    for (int r = 0; r < 4; ++r) {
      size_t mrow = (size_t)(m0 + i * 16 + quad * 4 + r) * N;
#pragma unroll
      for (int j = 0; j < 2; ++j)
        C[mrow + narr[j]] = f2bf(acc[i][j][r] + bvj[j]);
    }
}

// ---------------- scores via MFMA, register-direct Kt, fused softmax ----------------
__global__ __launch_bounds__(256) void score_mfma(const u16* __restrict__ Qb16,
                                                  const u16* __restrict__ Kt,
                                                  const int* __restrict__ mask,
                                                  float* __restrict__ Sout) {
  __shared__ u16 Qs[16 * 776];
  int t = threadIdx.x, wave = t >> 6, lane = t & 63, l16 = lane & 15, quad = lane >> 4;
  int m0 = blockIdx.x * 64;
#pragma unroll
  for (int r = 0; r < 6; ++r) {
    int idx = t + 256 * r;
    int row = idx / 96, c8 = idx % 96;
    *(short8*)&Qs[row * 776 + c8 * 8] = *(const short8*)&Qb16[row * 768 + c8 * 8];
  }
  __syncthreads();
  int row = m0 + wave * 16 + l16;
  const u16* kp = Kt + (size_t)row * 768 + quad * 8;
  f32x4 acc = {0.f, 0.f, 0.f, 0.f};
#pragma unroll
  for (int it = 0; it < 24; ++it) {
    short8 fa = *(const short8*)(kp + it * 32);
    short8 fb = *(const short8*)&Qs[l16 * 776 + it * 32 + quad * 8];
    acc = __builtin_amdgcn_mfma_f32_16x16x32_bf16(fa, fb, acc, 0, 0, 0);
  }
  const float scale = 0.1020620726159658f;  // (768/8)^-0.5
#pragma unroll
  for (int r = 0; r < 4; ++r) {
    int orow = m0 + wave * 16 + quad * 4 + r;
    float s = acc[r] * scale;
    if (mask[orow] == 0) s = -3.402823466e38f;  // finfo(f32).min
    float mx = s;
#pragma unroll
    for (int off = 1; off < 16; off <<= 1) mx = fmaxf(mx, __shfl_xor(mx, off));
    float e = __expf(s - mx);
    float sm = e;
#pragma unroll
    for (int off = 1; off < 16; off <<= 1) sm += __shfl_xor(sm, off);
    Sout[(size_t)orow * 16 + l16] = e / sm;
  }
}

// ---------------- PV: V = S^T @ Vt, gate blend. grid (256, 3) ----------------
__global__ __launch_bounds__(256) void pv_kernel(const float* __restrict__ Sg,
                                                 const u16* __restrict__ Vt,
                                                 const float* __restrict__ nq,
                                                 const float* __restrict__ gatep,
                                                 float* __restrict__ V32,
                                                 u16* __restrict__ V16) {
  __shared__ float Ss[1232];
  int b = blockIdx.x, t = threadIdx.x;
  int d = blockIdx.y * 256 + t;
#pragma unroll
  for (int r = 0; r < 5; ++r) {
    int idx = t + 256 * r;
    if (idx < 1232) Ss[idx] = Sg[(size_t)b * 1232 + idx];
  }
  __syncthreads();
  float a[16];
#pragma unroll
  for (int k = 0; k < 16; ++k) a[k] = 0.f;
  const u16* vt = Vt + (size_t)b * 77 * 768;
  for (int n = 0; n < 77; ++n) {
    float g = bf2f(vt[(size_t)n * 768 + d]);
    const float* sr = &Ss[n * 16];
#pragma unroll
    for (int k = 0; k < 16; ++k) a[k] += sr[k] * g;
  }
  float gv = gatep[0];
  float gate = 1.f / (1.f + __expf(-gv));
  float og = 1.f - gate;
#pragma unroll
  for (int k = 0; k < 16; ++k) {
    float val = og * a[k] + gate * nq[k * 768 + d];
    size_t idx = (size_t)b * 12288 + (size_t)k * 768 + d;
    V32[idx] = val;
    V16[idx] = f2bf(val);
  }
}

// ---------------- edge logits (+softmax) per batch; HIJ bf16 ----------------
__global__ __launch_bounds__(256) void edge_kernel(const u16* __restrict__ HIJ,
                                                   const float* __restrict__ be1,
                                                   const float* __restrict__ We2,
                                                   const float* __restrict__ be2v,
                                                   float* __restrict__ Aout,
                                                   float* __restrict__ Eout) {
  __shared__ float hiS[16 * 260];
  __shared__ float hjS[16 * 260];
  __shared__ float be1s[512];
  __shared__ float w2s[512];
  int b = blockIdx.x, t = threadIdx.x;
  be1s[t] = be1[t]; be1s[t + 256] = be1[t + 256];
  w2s[t] = We2[t];  w2s[t + 256] = We2[t + 256];

  int i = t >> 4, jj = t & 15;
  float e = 0.f;
  for (int half = 0; half < 2; ++half) {
    __syncthreads();
#pragma unroll
    for (int r = 0; r < 2; ++r) {
      int idx = t + 256 * r;          // 512 short8 chunks per half
      int row = idx >> 5, c8 = idx & 31;
      const u16* src = &HIJ[(size_t)(b * 16 + row) * 1024 + half * 256 + c8 * 8];
      short8 hv = *(const short8*)src;
      short8 jv = *(const short8*)(src + 512);
      f32x4 l0, l1, m0v, m1v;
#pragma unroll
      for (int ee = 0; ee < 4; ++ee) {
        l0[ee] = bf2f((u16)hv[ee]); l1[ee] = bf2f((u16)hv[ee + 4]);
        m0v[ee] = bf2f((u16)jv[ee]); m1v[ee] = bf2f((u16)jv[ee + 4]);
      }
      *(f32x4*)&hiS[row * 260 + c8 * 8] = l0;
      *(f32x4*)&hiS[row * 260 + c8 * 8 + 4] = l1;
      *(f32x4*)&hjS[row * 260 + c8 * 8] = m0v;
      *(f32x4*)&hjS[row * 260 + c8 * 8 + 4] = m1v;
    }
    __syncthreads();
    const float* hi = &hiS[i * 260];
    const float* hj = &hjS[jj * 260];
    const float* b1 = &be1s[half * 256];
    const float* w2 = &w2s[half * 256];
#pragma unroll 2
    for (int h4 = 0; h4 < 64; ++h4) {
      f32x4 hv = *(const f32x4*)&hi[h4 * 4];
      f32x4 jv = *(const f32x4*)&hj[h4 * 4];
      f32x4 bv = *(const f32x4*)&b1[h4 * 4];
      f32x4 wv = *(const f32x4*)&w2[h4 * 4];
#pragma unroll
      for (int ee = 0; ee < 4; ++ee)
        e += fmaxf(hv[ee] + jv[ee] + bv[ee], 0.f) * wv[ee];
    }
  }
  e += be2v[0];

  if (Aout) {
    float mx = e;
#pragma unroll
    for (int off = 1; off < 16; off <<= 1) mx = fmaxf(mx, __shfl_xor(mx, off));
    float ex = __expf(e - mx);
    float sm = ex;
#pragma unroll
    for (int off = 1; off < 16; off <<= 1) sm += __shfl_xor(sm, off);
    Aout[(size_t)b * 256 + t] = ex / sm;
  }
  if (Eout) Eout[(size_t)b * 256 + t] = e;
}

// ---------------- GNN combine: V += relu(A @ G); G bf16 ----------------
__global__ __launch_bounds__(256) void combine_kernel(const float* __restrict__ Aws,
                                                      const u16* __restrict__ G,
                                                      float* __restrict__ V32,
                                                      u16* __restrict__ V16,
                                                      float* __restrict__ Vout) {
  __shared__ float Gs[16 * 772];
  __shared__ float As[256];
  int b = blockIdx.x, t = threadIdx.x;
#pragma unroll
  for (int r = 0; r < 6; ++r) {
    int idx = t + 256 * r;
    int row = idx / 96, c8 = idx % 96;
    short8 gv8 = *(const short8*)&G[(size_t)(b * 16 + row) * 768 + c8 * 8];
    f32x4 l0, l1;
#pragma unroll
    for (int ee = 0; ee < 4; ++ee) { l0[ee] = bf2f((u16)gv8[ee]); l1[ee] = bf2f((u16)gv8[ee + 4]); }
    *(f32x4*)&Gs[row * 772 + c8 * 8] = l0;
    *(f32x4*)&Gs[row * 772 + c8 * 8 + 4] = l1;
  }
  As[t] = Aws[(size_t)b * 256 + t];
  __syncthreads();
#pragma unroll
  for (int m = 0; m < 3; ++m) {
    int d = t + m * 256;
    float gv[16];
#pragma unroll
    for (int j = 0; j < 16; ++j) gv[j] = Gs[j * 772 + d];
#pragma unroll
    for (int i = 0; i < 16; ++i) {
      float msg = 0.f;
#pragma unroll
      for (int j = 0; j < 16; ++j) msg += As[i * 16 + j] * gv[j];
      size_t idx = (size_t)b * 12288 + (size_t)i * 768 + d;
      float v = V32[idx] + fmaxf(msg, 0.f);
      V32[idx] = v;
      V16[idx] = f2bf(v);
      if (Vout) Vout[idx] = v;
    }
  }
}

extern "C" void kernel_launch(void* const* d_in, const int* in_sizes, int n_in,
                              void* d_out, int out_size, void* d_ws, size_t ws_size,
                              hipStream_t stream) {
  const float* w    = (const float*)d_in[0];   // [256,77,768]
  const int*   mask = (const int*)d_in[1];     // [256,77]
  const float* nq   = (const float*)d_in[2];   // [1,16,768]
  const float* Wq   = (const float*)d_in[3];
  const float* bq   = (const float*)d_in[4];
  const float* Wk   = (const float*)d_in[5];
  const float* bk   = (const float*)d_in[6];
  const float* Wv   = (const float*)d_in[7];
  const float* bv   = (const float*)d_in[8];
  const float* We1  = (const float*)d_in[9];   // [1536,512]
  const float* be1  = (const float*)d_in[10];
  const float* We2  = (const float*)d_in[11];  // [512,1]
  const float* be2  = (const float*)d_in[12];
  const float* gate = (const float*)d_in[13];
  const float* Wg   = (const float*)d_in[14];  // [2,768,768]
  const float* bg   = (const float*)d_in[15];  // [2,768]

  // workspace (~86.4 MB)
  float* ws    = (float*)d_ws;
  float* V32   = ws;                    // 3,145,728 f
  float* Aws   = V32 + 3145728;         // 65,536 f
  float* Qpart = Aws + 65536;           // 98,304 f
  u16* Qb16    = (u16*)(Qpart + 98304); // 12,288 u16
  u16* WkvT    = Qb16 + 12288;          // 1,179,648
  u16* We1T    = WkvT + 1179648;        // 786,432
  u16* WgT     = We1T + 786432;         // 1,179,648
  u16* V16     = WgT + 1179648;         // 3,145,728
  u16* w16     = V16 + 3145728;         // 15,138,816 (dead after V-gemm)
  u16* KVt     = w16 + 15138816;        // 15,138,816 (Kt then Vt; dead after pv)
  // unions into dead w16 region (after pv):
  u16* HIJ     = w16;                   // 4,194,304 u16
  u16* Gws     = w16 + 4194304;         // 3,145,728 u16

  float* out  = (float*)d_out;
  float* Sout = out;                       // [256,77,16]
  float* Vout = out + 315392;              // [256,16,768]
  float* Eout = out + 315392 + 3145728;    // [256,16,16]

  dim3 blk(256);

  // prep: weights -> bf16 [n][k]; w -> bf16; Q -> bf16 (split-K)
  tcast_all<<<dim3(24, 24, 6), blk, 0, stream>>>(Wk, Wv, We1, Wg, WkvT, We1T, WgT);
  wcast_k<<<7392, blk, 0, stream>>>(w, w16, 1892352);
  q_part<<<dim3(48, 8), blk, 0, stream>>>(nq, Wq, Qpart);
  q_reduce<<<48, blk, 0, stream>>>(Qpart, bq, Qb16);

  // Kt = w16 @ WkT + bk ; scores+softmax -> Sout
  gemm16<<<924, blk, 0, stream>>>(w16, WkvT, bk, KVt, 768, 768, 154, 6);
  score_mfma<<<308, blk, 0, stream>>>(Qb16, KVt, mask, Sout);

  // Vt = w16 @ WvT + bv (same buffer) ; V = S^T Vt + gate blend
  gemm16<<<924, blk, 0, stream>>>(w16, WkvT + 589824, bv, KVt, 768, 768, 154, 6);
  pv_kernel<<<dim3(256, 3), blk, 0, stream>>>(Sout, KVt, nq, gate, V32, V16);

  // fused: pre-GNN edge gemm (HIJ, 8 n-tiles) + GNN layer-0 gemm (Gws, 6 n-tiles)
  gemm16s<<<896, blk, 0, stream>>>(V16, We1T, nullptr, HIJ, 1024, 8,
                                   WgT, bg, Gws, 768, 6, 768);
  edge_kernel<<<256, blk, 0, stream>>>(HIJ, be1, We2, be2, Aws, (float*)nullptr);
  combine_kernel<<<256, blk, 0, stream>>>(Aws, Gws, V32, V16, (float*)nullptr);

  // GNN layer 1
  gemm16s<<<384, blk, 0, stream>>>(V16, WgT + 589824, bg + 768, Gws, 768, 6,
                                   WgT + 589824, bg + 768, Gws, 768, 0, 768);
  combine_kernel<<<256, blk, 0, stream>>>(Aws, Gws, V32, V16, Vout);

  // post-GNN edge logits -> E
  gemm16s<<<512, blk, 0, stream>>>(V16, We1T, nullptr, HIJ, 1024, 8,
                                   We1T, nullptr, HIJ, 1024, 0, 768);
  edge_kernel<<<256, blk, 0, stream>>>(HIJ, be1, We2, be2, (float*)nullptr, Eout);
}